// Round 15
// baseline (421.897 us; speedup 1.0000x reference)
//
#include <hip/hip_runtime.h>
#include <hip/hip_bf16.h>

typedef __attribute__((ext_vector_type(8))) short short8;
typedef __attribute__((ext_vector_type(4))) short short4x;
typedef __attribute__((ext_vector_type(4))) float floatx4;

#define MFMA16(a,b,c) __builtin_amdgcn_mfma_f32_16x16x32_bf16((a),(b),(c),0,0,0)

__device__ __forceinline__ unsigned short f2bf(float f) {
  unsigned int x = __float_as_uint(f);
  return (unsigned short)((x + 0x7fffu + ((x >> 16) & 1u)) >> 16);
}
__device__ __forceinline__ float bf2f(unsigned short s) {
  return __uint_as_float(((unsigned int)s) << 16);
}
__device__ __forceinline__ unsigned short f2bf_cvt(float f) {
  unsigned int r;
  asm("v_cvt_pk_bf16_f32 %0, %1, %1" : "=v"(r) : "v"(f));
  return (unsigned short)r;
}
__device__ __forceinline__ short8 pack8(float4 f0, float4 f1) {
  union { unsigned int u[4]; short8 s; } r;
  asm("v_cvt_pk_bf16_f32 %0, %1, %2" : "=v"(r.u[0]) : "v"(f0.x), "v"(f0.y));
  asm("v_cvt_pk_bf16_f32 %0, %1, %2" : "=v"(r.u[1]) : "v"(f0.z), "v"(f0.w));
  asm("v_cvt_pk_bf16_f32 %0, %1, %2" : "=v"(r.u[2]) : "v"(f1.x), "v"(f1.y));
  asm("v_cvt_pk_bf16_f32 %0, %1, %2" : "=v"(r.u[3]) : "v"(f1.z), "v"(f1.w));
  return r.s;
}

// ---------------------------------------------------------------- prep
__global__ __launch_bounds__(256)
void prep_kernel(const float* __restrict__ Wq, const float* __restrict__ Wk,
                 const float* __restrict__ Wv, const float* __restrict__ W1,
                 const float* __restrict__ b1, const float* __restrict__ W2,
                 const float* __restrict__ b2, const float* __restrict__ Wqc,
                 const float* __restrict__ bqc, const float* __restrict__ Wkc,
                 const float* __restrict__ bkc, const float* __restrict__ sf,
                 const float* __restrict__ pos,
                 unsigned short* __restrict__ Wf, unsigned short* __restrict__ Ut,
                 float* __restrict__ cqck, float* __restrict__ Asf,
                 float* __restrict__ Ppos)
{
  int blk = blockIdx.x, t = threadIdx.x;
  if (blk < 24) {
    int mat = blk >> 3, cg = blk & 7;
    const float* W = (mat == 0) ? Wq : (mat == 1) ? Wk : Wv;
    int l = t & 63, jp = t >> 6;
    int col = cg * 16 + (l & 15);
    unsigned short* o = Wf + (size_t)mat * 131072 + (size_t)cg * 32 * 512 + l * 8 + jp * 2;
    for (int ks = 0; ks < 32; ++ks) {
      int k = ks * 32 + (l >> 4) * 8 + jp * 2;
      o[ks * 512 + 0] = f2bf(W[(size_t)k * 128 + col]);
      o[ks * 512 + 1] = f2bf(W[(size_t)(k + 1) * 128 + col]);
    }
  } else if (blk >= 384 && blk < 512) {
    int j = blk - 384;
    int k = t & 127;
    const float* Wc = (t < 128) ? Wqc : Wkc;
    float acc = 0.f;
    for (int h = 0; h < 128; ++h) acc += W2[k * 128 + h] * Wc[h * 128 + j];
    Ut[(size_t)((t < 128) ? j : 128 + j) * 128 + k] = f2bf(acc);
  } else if (blk == 512) {
    int j = t & 127;
    const float* Wc = (t < 128) ? Wqc : Wkc;
    const float* bc = (t < 128) ? bqc : bkc;
    float acc = bc[j];
    for (int k = 0; k < 128; ++k) acc += b2[k] * Wc[k * 128 + j];
    cqck[t] = acc;
  } else if (blk > 512 && blk < 529) {
    int b = blk - 513;
    if (t < 128) {
      float acc = 0.f;
      for (int i = 0; i < 64; ++i) acc += sf[b * 64 + i] * W1[i * 128 + t];
      Asf[b * 128 + t] = acc;
    }
  } else if (blk >= 529) {
    int l = blk - 529;
    if (t < 128) {
      float acc = b1[t];
      for (int i = 0; i < 32; ++i) acc += pos[l * 32 + i] * W1[(64 + i) * 128 + t];
      Ppos[l * 128 + t] = acc;
    }
  }
}

// ---------------------------------------------------------------- projections (R13 form)
__global__ __launch_bounds__(256)
void proj_kernel(const float* __restrict__ X, const unsigned short* __restrict__ Wf,
                 const float* __restrict__ bias,
                 unsigned short* __restrict__ qo, unsigned short* __restrict__ ko,
                 unsigned short* __restrict__ vto, int which)
{
  __shared__ __align__(16) unsigned short X_lds[32 * 1032];   // 66048 B

  int t = threadIdx.x, w = t >> 6, l = t & 63;
  int rowbase = blockIdx.x * 32;
  const int lrow = l & 15, hi = l >> 4;
  const float RS2 = 0.08838834764831845f * 1.4426950408889634f;

#pragma unroll
  for (int r = 0; r < 8; ++r) {
    int row = w * 8 + r;
    const float* src = X + (size_t)(rowbase + row) * 1024 + l * 4;
    unsigned short* dst = &X_lds[row * 1032 + l * 4];
#pragma unroll
    for (int i = 0; i < 4; ++i) {
      float4 v = *(const float4*)(src + i * 256);
      short4x s;
      s[0] = (short)f2bf(v.x); s[1] = (short)f2bf(v.y);
      s[2] = (short)f2bf(v.z); s[3] = (short)f2bf(v.w);
      *(short4x*)(dst + i * 256) = s;
    }
  }
  __syncthreads();

  const unsigned short* wp0 = Wf + (size_t)(w * 2) * 32 * 512 + l * 8;
  const unsigned short* wp1 = Wf + (size_t)(w * 2 + 1) * 32 * 512 + l * 8;
  const int xo0 = lrow * 1032 + hi * 8;
  const int xo1 = (lrow + 16) * 1032 + hi * 8;

  floatx4 acc[2][2];
#pragma unroll
  for (int i = 0; i < 2; ++i)
#pragma unroll
    for (int j = 0; j < 2; ++j) { acc[i][j][0]=0.f; acc[i][j][1]=0.f; acc[i][j][2]=0.f; acc[i][j][3]=0.f; }

#pragma unroll 4
  for (int ks = 0; ks < 32; ++ks) {
    short8 b0 = *(const short8*)(wp0 + ks * 512);
    short8 b1 = *(const short8*)(wp1 + ks * 512);
    short8 a0 = *(const short8*)&X_lds[xo0 + ks * 32];
    short8 a1 = *(const short8*)&X_lds[xo1 + ks * 32];
    acc[0][0] = MFMA16(a0, b0, acc[0][0]);
    acc[0][1] = MFMA16(a0, b1, acc[0][1]);
    acc[1][0] = MFMA16(a1, b0, acc[1][0]);
    acc[1][1] = MFMA16(a1, b1, acc[1][1]);
  }

#pragma unroll
  for (int mf = 0; mf < 2; ++mf)
#pragma unroll
    for (int nf = 0; nf < 2; ++nf) {
      int col = w * 32 + nf * 16 + lrow;
      float bb = bias[col];
#pragma unroll
      for (int j = 0; j < 4; ++j) {
        int grow = rowbase + mf * 16 + hi * 4 + j;
        float v = acc[mf][nf][j] + bb;
        if (which == 0) qo[(size_t)grow * 128 + col] = f2bf(v * RS2);
        else if (which == 1) ko[(size_t)grow * 128 + col] = f2bf(v);
        else {
          int b = grow >> 11, li = grow & 2047;
          vto[((size_t)b * 128 + col) * 2048 + li] = f2bf(v);
        }
      }
    }
}

// ---------------------------------------------------------------- qc / kc
__global__ __launch_bounds__(256)
void qckc_kernel(const float* __restrict__ Asf, const float* __restrict__ Ppos,
                 const unsigned short* __restrict__ Ut, const float* __restrict__ cqck,
                 unsigned short* __restrict__ qc, unsigned short* __restrict__ kc)
{
  __shared__ __align__(16) unsigned short hid[64 * 136];
  int t = threadIdx.x, w = t >> 6, l = t & 63;
  int lbase = blockIdx.x * 64;
  int b = lbase >> 11;
  const int lrow = l & 15, lk = (l >> 4) * 8;
  {
    int r = t >> 2, seg = (t & 3) * 32;
    const float* pp = Ppos + (size_t)((lbase + r) & 2047) * 128 + seg;
    const float* aa = Asf + b * 128 + seg;
    unsigned short* dst = hid + r * 136 + seg;
#pragma unroll
    for (int c = 0; c < 32; c += 4) {
      float4 p4 = *(const float4*)(pp + c);
      float4 a4 = *(const float4*)(aa + c);
      dst[c + 0] = f2bf(fmaxf(p4.x + a4.x, 0.f));
      dst[c + 1] = f2bf(fmaxf(p4.y + a4.y, 0.f));
      dst[c + 2] = f2bf(fmaxf(p4.z + a4.z, 0.f));
      dst[c + 3] = f2bf(fmaxf(p4.w + a4.w, 0.f));
    }
  }
  __syncthreads();
  short8 a[4];
#pragma unroll
  for (int ks = 0; ks < 4; ++ks)
    a[ks] = *(const short8*)&hid[(w * 16 + lrow) * 136 + ks * 32 + lk];
  floatx4 acc[16];
#pragma unroll
  for (int nf = 0; nf < 16; ++nf) { acc[nf][0]=0.f; acc[nf][1]=0.f; acc[nf][2]=0.f; acc[nf][3]=0.f; }
#pragma unroll
  for (int nf = 0; nf < 16; ++nf)
#pragma unroll
    for (int ks = 0; ks < 4; ++ks) {
      short8 bfr = *(const short8*)(Ut + (size_t)(nf * 16 + lrow) * 128 + ks * 32 + lk);
      acc[nf] = MFMA16(a[ks], bfr, acc[nf]);
    }
#pragma unroll
  for (int nf = 0; nf < 16; ++nf) {
    int col = nf * 16 + lrow;
    float bb = cqck[col];
#pragma unroll
    for (int j = 0; j < 4; ++j) {
      int grow = lbase + w * 16 + (l >> 4) * 4 + j;
      float v = acc[nf][j] + bb;
      if (col < 128) qc[(size_t)grow * 128 + col] = f2bf(v);
      else kc[(size_t)grow * 128 + (col - 128)] = f2bf(v);
    }
  }
}

// ---------------------------------------------------------------- M2 partial
__global__ __launch_bounds__(256)
void m2_partial_kernel(const unsigned short* __restrict__ vt,
                       const unsigned short* __restrict__ kc,
                       float* __restrict__ M2p)
{
  __shared__ __align__(16) unsigned short kct[128 * 40];
  int ks = blockIdx.x, b = blockIdx.y;
  int t = threadIdx.x, w = t >> 6, l = t & 63;
  const int lrow = l & 15, lk = (l >> 4) * 8;
  floatx4 acc[2][8];
#pragma unroll
  for (int i = 0; i < 2; ++i)
#pragma unroll
    for (int j = 0; j < 8; ++j) { acc[i][j][0]=0.f; acc[i][j][1]=0.f; acc[i][j][2]=0.f; acc[i][j][3]=0.f; }
  for (int mc = 0; mc < 8; ++mc) {
    int mbase = ks * 256 + mc * 32;
    {
      int mm = t & 31, ib = (t >> 5) * 16;
      const unsigned short* src = kc + ((size_t)b * 2048 + mbase + mm) * 128 + ib;
#pragma unroll
      for (int ii = 0; ii < 16; ++ii) kct[(ib + ii) * 40 + mm] = src[ii];
    }
    __syncthreads();
#pragma unroll
    for (int mf = 0; mf < 2; ++mf) {
      int jrow = w * 32 + mf * 16 + lrow;
      short8 a = *(const short8*)(vt + ((size_t)b * 128 + jrow) * 2048 + mbase + lk);
#pragma unroll
      for (int nf = 0; nf < 8; ++nf) {
        short8 bfr = *(const short8*)&kct[(nf * 16 + lrow) * 40 + lk];
        acc[mf][nf] = MFMA16(a, bfr, acc[mf][nf]);
      }
    }
    __syncthreads();
  }
#pragma unroll
  for (int mf = 0; mf < 2; ++mf)
#pragma unroll
    for (int nf = 0; nf < 8; ++nf)
#pragma unroll
      for (int j = 0; j < 4; ++j) {
        int jr = w * 32 + mf * 16 + (l >> 4) * 4 + j;
        int ic = nf * 16 + lrow;
        M2p[(((size_t)ks * 16 + b) * 128 + jr) * 128 + ic] = acc[mf][nf][j];
      }
}

__global__ void m2_reduce_kernel(const float* __restrict__ M2p, float* __restrict__ M2t)
{
  int idx = blockIdx.x * 256 + threadIdx.x;
  float s = 0.f;
#pragma unroll
  for (int ksp = 0; ksp < 8; ++ksp) s += M2p[(size_t)ksp * 262144 + idx];
  M2t[idx] = s;
}

// ---------------------------------------------------------------- attention partial (split-KV, V in regs)
// grid (32,16,2). V tile fragments loaded straight from global (L2/L3) into
// registers right after the barrier — consumed by PV after QK^T+softmax hides
// their latency. No V_lds: LDS = K(17.4K) + P(9.2K) -> 4 blocks/CU with the
// 1024-block grid. K register-prefetch, defer-max THR=8, cvt_pk P-store.
__global__ __launch_bounds__(256)
void attn_partial_kernel(const unsigned short* __restrict__ qbf,
                         const unsigned short* __restrict__ kbf,
                         const unsigned short* __restrict__ vt,
                         float* __restrict__ op, float* __restrict__ ms)
{
  __shared__ __align__(16) unsigned short K_lds[64 * 136];
  __shared__ __align__(16) unsigned short P_lds[4 * 16 * 72];
  int t = threadIdx.x, w = t >> 6, l = t & 63;
  int lbase = blockIdx.x * 64, b = blockIdx.y, z = blockIdx.z;
  const int lrow = l & 15, lk = (l >> 4) * 8;

  size_t browq = (size_t)b * 2048 + lbase + w * 16 + lrow;
  short8 aq[4];
#pragma unroll
  for (int ks = 0; ks < 4; ++ks)
    aq[ks] = *(const short8*)(qbf + browq * 128 + ks * 32 + lk);

  float m_run[4] = {-1e30f, -1e30f, -1e30f, -1e30f};
  float s_run[4] = {0.f, 0.f, 0.f, 0.f};
  floatx4 o[8];
#pragma unroll
  for (int nf = 0; nf < 8; ++nf) { o[nf][0]=0.f; o[nf][1]=0.f; o[nf][2]=0.f; o[nf][3]=0.f; }

  int sr = t >> 2, sseg = (t & 3) * 32;

  const short8* ksrc0 = (const short8*)(kbf + ((size_t)b * 2048 + z * 1024 + sr) * 128 + sseg);
  // V fragment base: row nf*16+lrow of vt, tile col base z*1024 + kt*64 + kf*32 + lk
  const unsigned short* vfb = vt + ((size_t)b * 128 + lrow) * 2048 + z * 1024 + lk;

  short8 kr[4];
#pragma unroll
  for (int i = 0; i < 4; ++i) kr[i] = ksrc0[i];

  for (int kt = 0; kt < 16; ++kt) {
    {
      short8* dst = (short8*)&K_lds[sr * 136 + sseg];
      dst[0] = kr[0]; dst[1] = kr[1]; dst[2] = kr[2]; dst[3] = kr[3];
    }
    __syncthreads();
    if (kt < 15) {
      const short8* ks2 = ksrc0 + (size_t)(kt + 1) * 1024;
#pragma unroll
      for (int i = 0; i < 4; ++i) kr[i] = ks2[i];
    }
    // V fragments for CURRENT tile -> regs (latency hidden under QK+softmax)
    short8 vb[8][2];
#pragma unroll
    for (int nf = 0; nf < 8; ++nf)
#pragma unroll
      for (int kf = 0; kf < 2; ++kf)
        vb[nf][kf] = *(const short8*)(vfb + (size_t)(nf * 16) * 2048 + kt * 64 + kf * 32);
    floatx4 s[4];
    __builtin_amdgcn_s_setprio(1);
#pragma unroll
    for (int cf = 0; cf < 4; ++cf) {
      floatx4 a4; a4[0]=0.f; a4[1]=0.f; a4[2]=0.f; a4[3]=0.f;
#pragma unroll
      for (int ks = 0; ks < 4; ++ks) {
        short8 bfr = *(const short8*)&K_lds[(cf * 16 + lrow) * 136 + ks * 32 + lk];
        a4 = MFMA16(aq[ks], bfr, a4);
      }
      s[cf] = a4;
    }
    __builtin_amdgcn_s_setprio(0);
    float tm[4];
#pragma unroll
    for (int j = 0; j < 4; ++j) {
      float m0 = fmaxf(fmaxf(s[0][j], s[1][j]), fmaxf(s[2][j], s[3][j]));
#pragma unroll
      for (int off = 1; off < 16; off <<= 1) m0 = fmaxf(m0, __shfl_xor(m0, off, 64));
      tm[j] = m0;
    }
    bool need = (tm[0] > m_run[0] + 8.f) | (tm[1] > m_run[1] + 8.f) |
                (tm[2] > m_run[2] + 8.f) | (tm[3] > m_run[3] + 8.f);
    if (__any(need)) {
      float fmul[4];
#pragma unroll
      for (int j = 0; j < 4; ++j) {
        float nm = fmaxf(m_run[j], tm[j]);
        fmul[j] = exp2f(m_run[j] - nm);
        m_run[j] = nm;
        s_run[j] *= fmul[j];
      }
#pragma unroll
      for (int nf = 0; nf < 8; ++nf)
#pragma unroll
        for (int j = 0; j < 4; ++j) o[nf][j] *= fmul[j];
    }
#pragma unroll
    for (int j = 0; j < 4; ++j) {
      float rs = 0.f;
#pragma unroll
      for (int cf = 0; cf < 4; ++cf) {
        float p = exp2f(s[cf][j] - m_run[j]);
        s[cf][j] = p;
        rs += p;
      }
#pragma unroll
      for (int off = 1; off < 16; off <<= 1) rs += __shfl_xor(rs, off, 64);
      s_run[j] += rs;
    }
    unsigned short* pw = P_lds + w * (16 * 72);
#pragma unroll
    for (int cf = 0; cf < 4; ++cf)
#pragma unroll
      for (int j = 0; j < 4; ++j)
        pw[((l >> 4) * 4 + j) * 72 + cf * 16 + lrow] = f2bf_cvt(s[cf][j]);
    __builtin_amdgcn_s_setprio(1);
#pragma unroll
    for (int kf = 0; kf < 2; ++kf) {
      short8 ap = *(const short8*)&pw[lrow * 72 + kf * 32 + lk];
#pragma unroll
      for (int nf = 0; nf < 8; ++nf)
        o[nf] = MFMA16(ap, vb[nf][kf], o[nf]);
    }
    __builtin_amdgcn_s_setprio(0);
    __syncthreads();
  }
  size_t obase = (size_t)(z * 16 + b) * 2048;
#pragma unroll
  for (int nf = 0; nf < 8; ++nf)
#pragma unroll
    for (int j = 0; j < 4; ++j) {
      int grow = lbase + w * 16 + (l >> 4) * 4 + j;
      op[(obase + grow) * 128 + nf * 16 + lrow] = o[nf][j];
    }
  if (lrow == 0) {
#pragma unroll
    for (int j = 0; j < 4; ++j) {
      int row = lbase + w * 16 + (l >> 4) * 4 + j;
      ms[(obase + row) * 2 + 0] = m_run[j];
      ms[(obase + row) * 2 + 1] = s_run[j];
    }
  }
}

// ---------------------------------------------------------------- attention merge
__global__ __launch_bounds__(256)
void attn_merge_kernel(const float* __restrict__ op, const float* __restrict__ ms,
                       const unsigned short* __restrict__ qc,
                       const float* __restrict__ M2t, float* __restrict__ out)
{
  int t = threadIdx.x, w = t >> 6, l = t & 63;
  int lbase = blockIdx.x * 64, b = blockIdx.y;
  const int lrow = l & 15, lk = (l >> 4) * 8;
  size_t browq = (size_t)b * 2048 + lbase + w * 16 + lrow;

  float f0[4], f1[4], inv[4];
#pragma unroll
  for (int j = 0; j < 4; ++j) {
    int row = lbase + w * 16 + (l >> 4) * 4 + j;
    float m0 = ms[((size_t)(b) * 2048 + row) * 2 + 0];
    float s0 = ms[((size_t)(b) * 2048 + row) * 2 + 1];
    float m1 = ms[((size_t)(16 + b) * 2048 + row) * 2 + 0];
    float s1 = ms[((size_t)(16 + b) * 2048 + row) * 2 + 1];
    float M = fmaxf(m0, m1);
    f0[j] = exp2f(m0 - M);
    f1[j] = exp2f(m1 - M);
    inv[j] = 1.f / (s0 * f0[j] + s1 * f1[j]);
  }
  floatx4 o[8];
#pragma unroll
  for (int nf = 0; nf < 8; ++nf) {
    int col = nf * 16 + lrow;
#pragma unroll
    for (int j = 0; j < 4; ++j) {
      int grow = lbase + w * 16 + (l >> 4) * 4 + j;
      float o0 = op[((size_t)(b) * 2048 + grow) * 128 + col];
      float o1 = op[((size_t)(16 + b) * 2048 + grow) * 128 + col];
      o[nf][j] = (o0 * f0[j] + o1 * f1[j]) * inv[j];
    }
  }
#pragma unroll
  for (int ks = 0; ks < 4; ++ks) {
    short8 aqc = *(const short8*)(qc + browq * 128 + ks * 32 + lk);
#pragma unroll
    for (int nf = 0; nf < 8; ++nf) {
      const float* mp = M2t + ((size_t)b * 128 + nf * 16 + lrow) * 128 + ks * 32 + lk;
      float4 m0 = *(const float4*)(mp);
      float4 m1 = *(const float4*)(mp + 4);
      short8 bm = pack8(m0, m1);
      o[nf] = MFMA16(aqc, bm, o[nf]);
    }
  }
#pragma unroll
  for (int nf = 0; nf < 8; ++nf)
#pragma unroll
    for (int j = 0; j < 4; ++j) {
      int grow = lbase + w * 16 + (l >> 4) * 4 + j;
      out[((size_t)b * 2048 + grow) * 128 + nf * 16 + lrow] = o[nf][j];
    }
}

// ---------------------------------------------------------------- norm (fused z0+z1)
__global__ __launch_bounds__(256)
void norm_kernel(const unsigned short* __restrict__ qc, const unsigned short* __restrict__ kc,
                 float* __restrict__ partial)
{
  __shared__ __align__(16) unsigned short T1[129 * 136];
  __shared__ __align__(16) unsigned short T2[129 * 136];
  __shared__ float red[8];
  int t = threadIdx.x, w = t >> 6, l = t & 63;
  int ltm = blockIdx.x;
  int lt = ltm >> 4, mt = ltm & 15;
  int b = blockIdx.y;
  const int lrow = l & 15, lk = (l >> 4) * 8;
  {
    int r = t >> 1, half = (t & 1) * 64;
    const unsigned short* asrc = qc + ((size_t)b * 2048 + lt * 128 + r) * 128 + half;
    const unsigned short* bsrc = kc + ((size_t)b * 2048 + mt * 128 + r) * 128 + half;
    unsigned short* adst = T1 + r * 136 + half;
    unsigned short* bdst = T2 + r * 136 + half;
#pragma unroll
    for (int c = 0; c < 64; c += 8) {
      *(short8*)(adst + c) = *(const short8*)(asrc + c);
      *(short8*)(bdst + c) = *(const short8*)(bsrc + c);
    }
    if (t < 16) {
      int gr = lt * 128 + 128; if (gr > 2047) gr = 2047;
      *(short8*)(T1 + 128 * 136 + t * 8) =
          *(const short8*)(qc + ((size_t)b * 2048 + gr) * 128 + t * 8);
    } else if (t < 32) {
      int c = (t - 16) * 8;
      int gr = mt * 128 + 128; if (gr > 2047) gr = 2047;
      *(short8*)(T2 + 128 * 136 + c) =
          *(const short8*)(kc + ((size_t)b * 2048 + gr) * 128 + c);
    }
  }
  __syncthreads();
  floatx4 acc0[2][8], acc1[2][8];
#pragma unroll
  for (int i = 0; i < 2; ++i)
#pragma unroll
    for (int j = 0; j < 8; ++j) {
      acc0[i][j][0]=0.f; acc0[i][j][1]=0.f; acc0[i][j][2]=0.f; acc0[i][j][3]=0.f;
      acc1[i][j][0]=0.f; acc1[i][j][1]=0.f; acc1[i][j][2]=0.f; acc1[i][j][3]=0.f;
    }
#pragma unroll
  for (int ks = 0; ks < 4; ++ks) {
    int off = ks * 32 + lk;
    short8 ad[2], cd[2];
#pragma unroll
    for (int mf = 0; mf < 2; ++mf) {
      int r = w * 32 + mf * 16 + lrow;
      short8 x1 = *(const short8*)&T1[r * 136 + off];
      short8 y1 = *(const short8*)&T1[(r + 1) * 136 + off];
      short8 x2 = *(const short8*)&T2[r * 136 + off];
      short8 y2 = *(const short8*)&T2[(r + 1) * 136 + off];
      short8 d1, d2;
#pragma unroll
      for (int ii = 0; ii < 8; ++ii) {
        d1[ii] = (short)f2bf(bf2f((unsigned short)y1[ii]) - bf2f((unsigned short)x1[ii]));
        d2[ii] = (short)f2bf(bf2f((unsigned short)y2[ii]) - bf2f((unsigned short)x2[ii]));
      }
      ad[mf] = d1; cd[mf] = d2;
    }
#pragma unroll
    for (int nf = 0; nf < 8; ++nf) {
      short8 bk = *(const short8*)&T2[(nf * 16 + lrow) * 136 + off];
      short8 bq = *(const short8*)&T1[(nf * 16 + lrow) * 136 + off];
      acc0[0][nf] = MFMA16(ad[0], bk, acc0[0][nf]);
      acc0[1][nf] = MFMA16(ad[1], bk, acc0[1][nf]);
      acc1[0][nf] = MFMA16(cd[0], bq, acc1[0][nf]);
      acc1[1][nf] = MFMA16(cd[1], bq, acc1[1][nf]);
    }
  }
  float s0 = 0.f, s1 = 0.f;
#pragma unroll
  for (int i = 0; i < 2; ++i)
#pragma unroll
    for (int nf = 0; nf < 8; ++nf)
#pragma unroll
      for (int j = 0; j < 4; ++j) {
        s0 += fabsf(acc0[i][nf][j]);
        s1 += fabsf(acc1[i][nf][j]);
      }
#pragma unroll
  for (int off = 1; off < 64; off <<= 1) {
    s0 += __shfl_xor(s0, off, 64);
    s1 += __shfl_xor(s1, off, 64);
  }
  if (l == 0) { red[w] = s0; red[4 + w] = s1; }
  __syncthreads();
  if (t == 0) {
    partial[((size_t)0 * 16 + b) * 256 + ltm] = red[0] + red[1] + red[2] + red[3];
    partial[((size_t)1 * 16 + b) * 256 + ltm] = red[4] + red[5] + red[6] + red[7];
  }
}

__global__ void norm_reduce_kernel(const float* __restrict__ partial, float* __restrict__ outp)
{
  __shared__ float red[4];
  int t = threadIdx.x;
  float s = 0.f;
  for (int i = t; i < 8192; i += 256) s += partial[i];
#pragma unroll
  for (int off = 1; off < 64; off <<= 1) s += __shfl_xor(s, off, 64);
  if ((t & 63) == 0) red[t >> 6] = s;
  __syncthreads();
  if (t == 0) outp[0] = red[0] + red[1] + red[2] + red[3];
}

// ---------------------------------------------------------------- launch
extern "C" void kernel_launch(void* const* d_in, const int* in_sizes, int n_in,
                              void* d_out, int out_size, void* d_ws, size_t ws_size,
                              hipStream_t stream)
{
  const float* query = (const float*)d_in[0];
  const float* key_  = (const float*)d_in[1];
  const float* value = (const float*)d_in[2];
  const float* sf    = (const float*)d_in[3];
  const float* pos   = (const float*)d_in[4];
  const float* Wq  = (const float*)d_in[5];  const float* bq  = (const float*)d_in[6];
  const float* Wk  = (const float*)d_in[7];  const float* bk  = (const float*)d_in[8];
  const float* Wv  = (const float*)d_in[9];  const float* bv  = (const float*)d_in[10];
  const float* W1  = (const float*)d_in[11]; const float* b1  = (const float*)d_in[12];
  const float* W2  = (const float*)d_in[13]; const float* b2  = (const float*)d_in[14];
  const float* Wqc = (const float*)d_in[15]; const float* bqc = (const float*)d_in[16];
  const float* Wkc = (const float*)d_in[17]; const float* bkc = (const float*)d_in[18];
  float* out = (float*)d_out;

  char* ws = (char*)d_ws;
  size_t off = 0;
  auto alloc = [&](size_t bytes) {
    char* p = ws + off;
    off += (bytes + 255) & ~(size_t)255;
    return p;
  };
  unsigned short* Wf   = (unsigned short*)alloc((size_t)3 * 131072 * 2);
  unsigned short* Ut   = (unsigned short*)alloc((size_t)256 * 128 * 2);
  float* cqck          = (float*)alloc(256 * 4);
  float* Asf           = (float*)alloc(16 * 128 * 4);
  float* Ppos          = (float*)alloc((size_t)2048 * 128 * 4);
  unsigned short* qbf  = (unsigned short*)alloc((size_t)32768 * 128 * 2);
  unsigned short* kbf  = (unsigned short*)alloc((size_t)32768 * 128 * 2);
  unsigned short* vt   = (unsigned short*)alloc((size_t)32768 * 128 * 2);
  unsigned short* qc   = (unsigned short*)alloc((size_t)32768 * 128 * 2);
  unsigned short* kc   = (unsigned short*)alloc((size_t)32768 * 128 * 2);
  float* M2p           = (float*)alloc((size_t)8 * 262144 * 4);
  float* M2t           = (float*)alloc((size_t)262144 * 4);
  float* npartial      = (float*)alloc((size_t)8192 * 4);
  float* op            = (float*)alloc((size_t)32 * 2048 * 128 * 4);   // 32 MB
  float* ms            = (float*)alloc((size_t)32 * 2048 * 2 * 4);     // 512 KB
  (void)ws_size; (void)in_sizes; (void)n_in; (void)out_size;

  prep_kernel<<<2577, 256, 0, stream>>>(Wq, Wk, Wv, W1, b1, W2, b2, Wqc, bqc, Wkc, bkc,
                                        sf, pos, Wf, Ut, cqck, Asf, Ppos);
  proj_kernel<<<1024, 256, 0, stream>>>(query, Wf,          bq, qbf, kbf, vt, 0);
  proj_kernel<<<1024, 256, 0, stream>>>(key_,  Wf + 131072, bk, qbf, kbf, vt, 1);
  proj_kernel<<<1024, 256, 0, stream>>>(value, Wf + 262144, bv, qbf, kbf, vt, 2);
  qckc_kernel<<<512, 256, 0, stream>>>(Asf, Ppos, Ut, cqck, qc, kc);
  m2_partial_kernel<<<dim3(8, 16), 256, 0, stream>>>(vt, kc, M2p);
  m2_reduce_kernel<<<1024, 256, 0, stream>>>(M2p, M2t);
  attn_partial_kernel<<<dim3(32, 16, 2), 256, 0, stream>>>(qbf, kbf, vt, op, ms);
  attn_merge_kernel<<<dim3(32, 16), 256, 0, stream>>>(op, ms, qc, M2t, out);
  norm_kernel<<<dim3(256, 16), 256, 0, stream>>>(qc, kc, npartial);
  norm_reduce_kernel<<<1, 256, 0, stream>>>(npartial, out + (size_t)4194304);
}

// Round 16
// 354.765 us; speedup vs baseline: 1.1892x; 1.1892x over previous
//
#include <hip/hip_runtime.h>
#include <hip/hip_bf16.h>

typedef __attribute__((ext_vector_type(8))) short short8;
typedef __attribute__((ext_vector_type(4))) short short4x;
typedef __attribute__((ext_vector_type(4))) float floatx4;

#define MFMA16(a,b,c) __builtin_amdgcn_mfma_f32_16x16x32_bf16((a),(b),(c),0,0,0)

__device__ __forceinline__ unsigned short f2bf(float f) {
  unsigned int x = __float_as_uint(f);
  return (unsigned short)((x + 0x7fffu + ((x >> 16) & 1u)) >> 16);
}
__device__ __forceinline__ float bf2f(unsigned short s) {
  return __uint_as_float(((unsigned int)s) << 16);
}
__device__ __forceinline__ unsigned short f2bf_cvt(float f) {
  unsigned int r;
  asm("v_cvt_pk_bf16_f32 %0, %1, %1" : "=v"(r) : "v"(f));
  return (unsigned short)r;
}

// ---------------------------------------------------------------- prep
__global__ __launch_bounds__(256)
void prep_kernel(const float* __restrict__ Wq, const float* __restrict__ Wk,
                 const float* __restrict__ Wv, const float* __restrict__ W1,
                 const float* __restrict__ b1, const float* __restrict__ W2,
                 const float* __restrict__ b2, const float* __restrict__ Wqc,
                 const float* __restrict__ bqc, const float* __restrict__ Wkc,
                 const float* __restrict__ bkc, const float* __restrict__ sf,
                 const float* __restrict__ pos,
                 unsigned short* __restrict__ Wf, unsigned short* __restrict__ Ut,
                 float* __restrict__ cqck, float* __restrict__ Asf,
                 float* __restrict__ Ppos)
{
  int blk = blockIdx.x, t = threadIdx.x;
  if (blk < 24) {
    int mat = blk >> 3, cg = blk & 7;
    const float* W = (mat == 0) ? Wq : (mat == 1) ? Wk : Wv;
    int l = t & 63, jp = t >> 6;
    int col = cg * 16 + (l & 15);
    unsigned short* o = Wf + (size_t)mat * 131072 + (size_t)cg * 32 * 512 + l * 8 + jp * 2;
    for (int ks = 0; ks < 32; ++ks) {
      int k = ks * 32 + (l >> 4) * 8 + jp * 2;
      o[ks * 512 + 0] = f2bf(W[(size_t)k * 128 + col]);
      o[ks * 512 + 1] = f2bf(W[(size_t)(k + 1) * 128 + col]);
    }
  } else if (blk >= 384 && blk < 512) {
    int j = blk - 384;
    int k = t & 127;
    const float* Wc = (t < 128) ? Wqc : Wkc;
    float acc = 0.f;
    for (int h = 0; h < 128; ++h) acc += W2[k * 128 + h] * Wc[h * 128 + j];
    Ut[(size_t)((t < 128) ? j : 128 + j) * 128 + k] = f2bf(acc);
  } else if (blk == 512) {
    int j = t & 127;
    const float* Wc = (t < 128) ? Wqc : Wkc;
    const float* bc = (t < 128) ? bqc : bkc;
    float acc = bc[j];
    for (int k = 0; k < 128; ++k) acc += b2[k] * Wc[k * 128 + j];
    cqck[t] = acc;
  } else if (blk > 512 && blk < 529) {
    int b = blk - 513;
    if (t < 128) {
      float acc = 0.f;
      for (int i = 0; i < 64; ++i) acc += sf[b * 64 + i] * W1[i * 128 + t];
      Asf[b * 128 + t] = acc;
    }
  } else if (blk >= 529) {
    int l = blk - 529;
    if (t < 128) {
      float acc = b1[t];
      for (int i = 0; i < 32; ++i) acc += pos[l * 32 + i] * W1[(64 + i) * 128 + t];
      Ppos[l * 128 + t] = acc;
    }
  }
}

// ---------------------------------------------------------------- projections (R13 form)
__global__ __launch_bounds__(256)
void proj_kernel(const float* __restrict__ X, const unsigned short* __restrict__ Wf,
                 const float* __restrict__ bias,
                 unsigned short* __restrict__ qo, unsigned short* __restrict__ ko,
                 unsigned short* __restrict__ vto, int which)
{
  __shared__ __align__(16) unsigned short X_lds[32 * 1032];   // 66048 B

  int t = threadIdx.x, w = t >> 6, l = t & 63;
  int rowbase = blockIdx.x * 32;
  const int lrow = l & 15, hi = l >> 4;
  const float RS2 = 0.08838834764831845f * 1.4426950408889634f;

#pragma unroll
  for (int r = 0; r < 8; ++r) {
    int row = w * 8 + r;
    const float* src = X + (size_t)(rowbase + row) * 1024 + l * 4;
    unsigned short* dst = &X_lds[row * 1032 + l * 4];
#pragma unroll
    for (int i = 0; i < 4; ++i) {
      float4 v = *(const float4*)(src + i * 256);
      short4x s;
      s[0] = (short)f2bf(v.x); s[1] = (short)f2bf(v.y);
      s[2] = (short)f2bf(v.z); s[3] = (short)f2bf(v.w);
      *(short4x*)(dst + i * 256) = s;
    }
  }
  __syncthreads();

  const unsigned short* wp0 = Wf + (size_t)(w * 2) * 32 * 512 + l * 8;
  const unsigned short* wp1 = Wf + (size_t)(w * 2 + 1) * 32 * 512 + l * 8;
  const int xo0 = lrow * 1032 + hi * 8;
  const int xo1 = (lrow + 16) * 1032 + hi * 8;

  floatx4 acc[2][2];
#pragma unroll
  for (int i = 0; i < 2; ++i)
#pragma unroll
    for (int j = 0; j < 2; ++j) { acc[i][j][0]=0.f; acc[i][j][1]=0.f; acc[i][j][2]=0.f; acc[i][j][3]=0.f; }

#pragma unroll 4
  for (int ks = 0; ks < 32; ++ks) {
    short8 b0 = *(const short8*)(wp0 + ks * 512);
    short8 b1 = *(const short8*)(wp1 + ks * 512);
    short8 a0 = *(const short8*)&X_lds[xo0 + ks * 32];
    short8 a1 = *(const short8*)&X_lds[xo1 + ks * 32];
    acc[0][0] = MFMA16(a0, b0, acc[0][0]);
    acc[0][1] = MFMA16(a0, b1, acc[0][1]);
    acc[1][0] = MFMA16(a1, b0, acc[1][0]);
    acc[1][1] = MFMA16(a1, b1, acc[1][1]);
  }

#pragma unroll
  for (int mf = 0; mf < 2; ++mf)
#pragma unroll
    for (int nf = 0; nf < 2; ++nf) {
      int col = w * 32 + nf * 16 + lrow;
      float bb = bias[col];
#pragma unroll
      for (int j = 0; j < 4; ++j) {
        int grow = rowbase + mf * 16 + hi * 4 + j;
        float v = acc[mf][nf][j] + bb;
        if (which == 0) qo[(size_t)grow * 128 + col] = f2bf(v * RS2);
        else if (which == 1) ko[(size_t)grow * 128 + col] = f2bf(v);
        else {
          int b = grow >> 11, li = grow & 2047;
          vto[((size_t)b * 128 + col) * 2048 + li] = f2bf(v);
        }
      }
    }
}

// ---------------------------------------------------------------- qc / kc
__global__ __launch_bounds__(256)
void qckc_kernel(const float* __restrict__ Asf, const float* __restrict__ Ppos,
                 const unsigned short* __restrict__ Ut, const float* __restrict__ cqck,
                 unsigned short* __restrict__ qc, unsigned short* __restrict__ kc)
{
  __shared__ __align__(16) unsigned short hid[64 * 136];
  int t = threadIdx.x, w = t >> 6, l = t & 63;
  int lbase = blockIdx.x * 64;
  int b = lbase >> 11;
  const int lrow = l & 15, lk = (l >> 4) * 8;
  {
    int r = t >> 2, seg = (t & 3) * 32;
    const float* pp = Ppos + (size_t)((lbase + r) & 2047) * 128 + seg;
    const float* aa = Asf + b * 128 + seg;
    unsigned short* dst = hid + r * 136 + seg;
#pragma unroll
    for (int c = 0; c < 32; c += 4) {
      float4 p4 = *(const float4*)(pp + c);
      float4 a4 = *(const float4*)(aa + c);
      dst[c + 0] = f2bf(fmaxf(p4.x + a4.x, 0.f));
      dst[c + 1] = f2bf(fmaxf(p4.y + a4.y, 0.f));
      dst[c + 2] = f2bf(fmaxf(p4.z + a4.z, 0.f));
      dst[c + 3] = f2bf(fmaxf(p4.w + a4.w, 0.f));
    }
  }
  __syncthreads();
  short8 a[4];
#pragma unroll
  for (int ks = 0; ks < 4; ++ks)
    a[ks] = *(const short8*)&hid[(w * 16 + lrow) * 136 + ks * 32 + lk];
  floatx4 acc[16];
#pragma unroll
  for (int nf = 0; nf < 16; ++nf) { acc[nf][0]=0.f; acc[nf][1]=0.f; acc[nf][2]=0.f; acc[nf][3]=0.f; }
#pragma unroll
  for (int nf = 0; nf < 16; ++nf)
#pragma unroll
    for (int ks = 0; ks < 4; ++ks) {
      short8 bfr = *(const short8*)(Ut + (size_t)(nf * 16 + lrow) * 128 + ks * 32 + lk);
      acc[nf] = MFMA16(a[ks], bfr, acc[nf]);
    }
#pragma unroll
  for (int nf = 0; nf < 16; ++nf) {
    int col = nf * 16 + lrow;
    float bb = cqck[col];
#pragma unroll
    for (int j = 0; j < 4; ++j) {
      int grow = lbase + w * 16 + (l >> 4) * 4 + j;
      float v = acc[nf][j] + bb;
      if (col < 128) qc[(size_t)grow * 128 + col] = f2bf(v);
      else kc[(size_t)grow * 128 + (col - 128)] = f2bf(v);
    }
  }
}

// ---------------------------------------------------------------- M2 partial
__global__ __launch_bounds__(256)
void m2_partial_kernel(const unsigned short* __restrict__ vt,
                       const unsigned short* __restrict__ kc,
                       float* __restrict__ M2p)
{
  __shared__ __align__(16) unsigned short kct[128 * 40];
  int ks = blockIdx.x, b = blockIdx.y;
  int t = threadIdx.x, w = t >> 6, l = t & 63;
  const int lrow = l & 15, lk = (l >> 4) * 8;
  floatx4 acc[2][8];
#pragma unroll
  for (int i = 0; i < 2; ++i)
#pragma unroll
    for (int j = 0; j < 8; ++j) { acc[i][j][0]=0.f; acc[i][j][1]=0.f; acc[i][j][2]=0.f; acc[i][j][3]=0.f; }
  for (int mc = 0; mc < 8; ++mc) {
    int mbase = ks * 256 + mc * 32;
    {
      int mm = t & 31, ib = (t >> 5) * 16;
      const unsigned short* src = kc + ((size_t)b * 2048 + mbase + mm) * 128 + ib;
#pragma unroll
      for (int ii = 0; ii < 16; ++ii) kct[(ib + ii) * 40 + mm] = src[ii];
    }
    __syncthreads();
#pragma unroll
    for (int mf = 0; mf < 2; ++mf) {
      int jrow = w * 32 + mf * 16 + lrow;
      short8 a = *(const short8*)(vt + ((size_t)b * 128 + jrow) * 2048 + mbase + lk);
#pragma unroll
      for (int nf = 0; nf < 8; ++nf) {
        short8 bfr = *(const short8*)&kct[(nf * 16 + lrow) * 40 + lk];
        acc[mf][nf] = MFMA16(a, bfr, acc[mf][nf]);
      }
    }
    __syncthreads();
  }
#pragma unroll
  for (int mf = 0; mf < 2; ++mf)
#pragma unroll
    for (int nf = 0; nf < 8; ++nf)
#pragma unroll
      for (int j = 0; j < 4; ++j) {
        int jr = w * 32 + mf * 16 + (l >> 4) * 4 + j;
        int ic = nf * 16 + lrow;
        M2p[(((size_t)ks * 16 + b) * 128 + jr) * 128 + ic] = acc[mf][nf][j];
      }
}

__global__ void m2_reduce_kernel(const float* __restrict__ M2p, float* __restrict__ M2t)
{
  int idx = blockIdx.x * 256 + threadIdx.x;
  float s = 0.f;
#pragma unroll
  for (int ksp = 0; ksp < 8; ++ksp) s += M2p[(size_t)ksp * 262144 + idx];
  M2t[idx] = s;
}

// ---------------------------------------------------------------- attention (R13 form + XCD swizzle)
// Flat grid 512. XCD-aware remap: xcd=id&7, seq=id>>3, batch=xcd*2+(seq>>5),
// qb=seq&31 -> each XCD serves exactly 2 batches; their K/V (2MB) fits the
// 4MB per-XCD L2 instead of 16 batches thrashing it.
__global__ __launch_bounds__(256)
void attn_kernel(const unsigned short* __restrict__ qbf, const unsigned short* __restrict__ kbf,
                 const unsigned short* __restrict__ vt, const unsigned short* __restrict__ qc,
                 const float* __restrict__ M2t, float* __restrict__ out)
{
  __shared__ __align__(16) unsigned short K_lds[64 * 136];
  __shared__ __align__(16) unsigned short V_lds[128 * 72];
  __shared__ __align__(16) unsigned short P_lds[4 * 16 * 72];
  int t = threadIdx.x, w = t >> 6, l = t & 63;
  int id = blockIdx.x;
  int xcd = id & 7, seq = id >> 3;
  int b = xcd * 2 + (seq >> 5);
  int lbase = (seq & 31) * 64;
  const int lrow = l & 15, lk = (l >> 4) * 8;

  size_t browq = (size_t)b * 2048 + lbase + w * 16 + lrow;
  short8 aq[4];
#pragma unroll
  for (int ks = 0; ks < 4; ++ks)
    aq[ks] = *(const short8*)(qbf + browq * 128 + ks * 32 + lk);

  float m_run[4] = {-1e30f, -1e30f, -1e30f, -1e30f};
  float s_run[4] = {0.f, 0.f, 0.f, 0.f};
  floatx4 o[8];
#pragma unroll
  for (int nf = 0; nf < 8; ++nf) { o[nf][0]=0.f; o[nf][1]=0.f; o[nf][2]=0.f; o[nf][3]=0.f; }

  int sr = t >> 2, sseg = (t & 3) * 32;
  int vr = t >> 1, vseg = (t & 1) * 32;

  const short8* ksrc0 = (const short8*)(kbf + ((size_t)b * 2048 + sr) * 128 + sseg);
  const short8* vsrc0 = (const short8*)(vt + ((size_t)b * 128 + vr) * 2048 + vseg);

  short8 kr[4], vrg[4];
#pragma unroll
  for (int i = 0; i < 4; ++i) { kr[i] = ksrc0[i]; vrg[i] = vsrc0[i]; }

  for (int kt = 0; kt < 32; ++kt) {
    {
      short8* dst = (short8*)&K_lds[sr * 136 + sseg];
      dst[0] = kr[0]; dst[1] = kr[1]; dst[2] = kr[2]; dst[3] = kr[3];
      short8* vdst = (short8*)&V_lds[vr * 72 + vseg];
      vdst[0] = vrg[0]; vdst[1] = vrg[1]; vdst[2] = vrg[2]; vdst[3] = vrg[3];
    }
    __syncthreads();
    if (kt < 31) {
      const short8* ks2 = ksrc0 + (size_t)(kt + 1) * 1024;
      const short8* vs2 = vsrc0 + (size_t)(kt + 1) * 8;
#pragma unroll
      for (int i = 0; i < 4; ++i) { kr[i] = ks2[i]; vrg[i] = vs2[i]; }
    }
    floatx4 s[4];
    __builtin_amdgcn_s_setprio(1);
#pragma unroll
    for (int cf = 0; cf < 4; ++cf) {
      floatx4 a4; a4[0]=0.f; a4[1]=0.f; a4[2]=0.f; a4[3]=0.f;
#pragma unroll
      for (int ks = 0; ks < 4; ++ks) {
        short8 bfr = *(const short8*)&K_lds[(cf * 16 + lrow) * 136 + ks * 32 + lk];
        a4 = MFMA16(aq[ks], bfr, a4);
      }
      s[cf] = a4;
    }
    __builtin_amdgcn_s_setprio(0);
    float tm[4];
#pragma unroll
    for (int j = 0; j < 4; ++j) {
      float m0 = fmaxf(fmaxf(s[0][j], s[1][j]), fmaxf(s[2][j], s[3][j]));
#pragma unroll
      for (int off = 1; off < 16; off <<= 1) m0 = fmaxf(m0, __shfl_xor(m0, off, 64));
      tm[j] = m0;
    }
    bool need = (tm[0] > m_run[0] + 8.f) | (tm[1] > m_run[1] + 8.f) |
                (tm[2] > m_run[2] + 8.f) | (tm[3] > m_run[3] + 8.f);
    if (__any(need)) {
      float fmul[4];
#pragma unroll
      for (int j = 0; j < 4; ++j) {
        float nm = fmaxf(m_run[j], tm[j]);
        fmul[j] = exp2f(m_run[j] - nm);
        m_run[j] = nm;
        s_run[j] *= fmul[j];
      }
#pragma unroll
      for (int nf = 0; nf < 8; ++nf)
#pragma unroll
        for (int j = 0; j < 4; ++j) o[nf][j] *= fmul[j];
    }
#pragma unroll
    for (int j = 0; j < 4; ++j) {
      float rs = 0.f;
#pragma unroll
      for (int cf = 0; cf < 4; ++cf) {
        float p = exp2f(s[cf][j] - m_run[j]);
        s[cf][j] = p;
        rs += p;
      }
#pragma unroll
      for (int off = 1; off < 16; off <<= 1) rs += __shfl_xor(rs, off, 64);
      s_run[j] += rs;
    }
    unsigned short* pw = P_lds + w * (16 * 72);
#pragma unroll
    for (int cf = 0; cf < 4; ++cf)
#pragma unroll
      for (int j = 0; j < 4; ++j)
        pw[((l >> 4) * 4 + j) * 72 + cf * 16 + lrow] = f2bf_cvt(s[cf][j]);
    __builtin_amdgcn_s_setprio(1);
#pragma unroll
    for (int kf = 0; kf < 2; ++kf) {
      short8 ap = *(const short8*)&pw[lrow * 72 + kf * 32 + lk];
#pragma unroll
      for (int nf = 0; nf < 8; ++nf) {
        short8 bv = *(const short8*)&V_lds[(nf * 16 + lrow) * 72 + kf * 32 + lk];
        o[nf] = MFMA16(ap, bv, o[nf]);
      }
    }
    __builtin_amdgcn_s_setprio(0);
    __syncthreads();
  }
  float inv[4];
#pragma unroll
  for (int j = 0; j < 4; ++j) inv[j] = 1.f / s_run[j];
#pragma unroll
  for (int nf = 0; nf < 8; ++nf)
#pragma unroll
    for (int j = 0; j < 4; ++j) o[nf][j] *= inv[j];
#pragma unroll
  for (int ks = 0; ks < 4; ++ks) {
    short8 aqc = *(const short8*)(qc + browq * 128 + ks * 32 + lk);
#pragma unroll
    for (int nf = 0; nf < 8; ++nf) {
      const float* mp = M2t + ((size_t)b * 128 + nf * 16 + lrow) * 128 + ks * 32 + lk;
      float4 m0 = *(const float4*)(mp);
      float4 m1 = *(const float4*)(mp + 4);
      short8 bm;
      bm[0]=(short)f2bf(m0.x); bm[1]=(short)f2bf(m0.y); bm[2]=(short)f2bf(m0.z); bm[3]=(short)f2bf(m0.w);
      bm[4]=(short)f2bf(m1.x); bm[5]=(short)f2bf(m1.y); bm[6]=(short)f2bf(m1.z); bm[7]=(short)f2bf(m1.w);
      o[nf] = MFMA16(aqc, bm, o[nf]);
    }
  }
#pragma unroll
  for (int nf = 0; nf < 8; ++nf)
#pragma unroll
    for (int j = 0; j < 4; ++j) {
      int grow = lbase + w * 16 + (l >> 4) * 4 + j;
      out[((size_t)b * 2048 + grow) * 128 + nf * 16 + lrow] = o[nf][j];
    }
}

// ---------------------------------------------------------------- norm (R13 form + XCD swizzle)
// Flat grid 4096: xcd=id&7, seq=id>>3, b=xcd*2+(seq>>8), ltm=seq&255 -> each
// XCD serves 2 batches' qc+kc (2MB, L2-fits).
__global__ __launch_bounds__(256)
void norm_kernel(const unsigned short* __restrict__ qc, const unsigned short* __restrict__ kc,
                 float* __restrict__ partial)
{
  __shared__ __align__(16) unsigned short T1[129 * 136];
  __shared__ __align__(16) unsigned short T2[129 * 136];
  __shared__ float red[8];
  int t = threadIdx.x, w = t >> 6, l = t & 63;
  int id = blockIdx.x;
  int xcd = id & 7, seq = id >> 3;
  int b = xcd * 2 + (seq >> 8);
  int ltm = seq & 255;
  int lt = ltm >> 4, mt = ltm & 15;
  const int lrow = l & 15, lk = (l >> 4) * 8;
  {
    int r = t >> 1, half = (t & 1) * 64;
    const unsigned short* asrc = qc + ((size_t)b * 2048 + lt * 128 + r) * 128 + half;
    const unsigned short* bsrc = kc + ((size_t)b * 2048 + mt * 128 + r) * 128 + half;
    unsigned short* adst = T1 + r * 136 + half;
    unsigned short* bdst = T2 + r * 136 + half;
#pragma unroll
    for (int c = 0; c < 64; c += 8) {
      *(short8*)(adst + c) = *(const short8*)(asrc + c);
      *(short8*)(bdst + c) = *(const short8*)(bsrc + c);
    }
    if (t < 16) {
      int gr = lt * 128 + 128; if (gr > 2047) gr = 2047;
      *(short8*)(T1 + 128 * 136 + t * 8) =
          *(const short8*)(qc + ((size_t)b * 2048 + gr) * 128 + t * 8);
    } else if (t < 32) {
      int c = (t - 16) * 8;
      int gr = mt * 128 + 128; if (gr > 2047) gr = 2047;
      *(short8*)(T2 + 128 * 136 + c) =
          *(const short8*)(kc + ((size_t)b * 2048 + gr) * 128 + c);
    }
  }
  __syncthreads();
  floatx4 acc0[2][8], acc1[2][8];
#pragma unroll
  for (int i = 0; i < 2; ++i)
#pragma unroll
    for (int j = 0; j < 8; ++j) {
      acc0[i][j][0]=0.f; acc0[i][j][1]=0.f; acc0[i][j][2]=0.f; acc0[i][j][3]=0.f;
      acc1[i][j][0]=0.f; acc1[i][j][1]=0.f; acc1[i][j][2]=0.f; acc1[i][j][3]=0.f;
    }
#pragma unroll
  for (int ks = 0; ks < 4; ++ks) {
    int off = ks * 32 + lk;
    short8 ad[2], cd[2];
#pragma unroll
    for (int mf = 0; mf < 2; ++mf) {
      int r = w * 32 + mf * 16 + lrow;
      short8 x1 = *(const short8*)&T1[r * 136 + off];
      short8 y1 = *(const short8*)&T1[(r + 1) * 136 + off];
      short8 x2 = *(const short8*)&T2[r * 136 + off];
      short8 y2 = *(const short8*)&T2[(r + 1) * 136 + off];
      short8 d1, d2;
#pragma unroll
      for (int ii = 0; ii < 8; ++ii) {
        d1[ii] = (short)f2bf(bf2f((unsigned short)y1[ii]) - bf2f((unsigned short)x1[ii]));
        d2[ii] = (short)f2bf(bf2f((unsigned short)y2[ii]) - bf2f((unsigned short)x2[ii]));
      }
      ad[mf] = d1; cd[mf] = d2;
    }
#pragma unroll
    for (int nf = 0; nf < 8; ++nf) {
      short8 bk = *(const short8*)&T2[(nf * 16 + lrow) * 136 + off];
      short8 bq = *(const short8*)&T1[(nf * 16 + lrow) * 136 + off];
      acc0[0][nf] = MFMA16(ad[0], bk, acc0[0][nf]);
      acc0[1][nf] = MFMA16(ad[1], bk, acc0[1][nf]);
      acc1[0][nf] = MFMA16(cd[0], bq, acc1[0][nf]);
      acc1[1][nf] = MFMA16(cd[1], bq, acc1[1][nf]);
    }
  }
  float s0 = 0.f, s1 = 0.f;
#pragma unroll
  for (int i = 0; i < 2; ++i)
#pragma unroll
    for (int nf = 0; nf < 8; ++nf)
#pragma unroll
      for (int j = 0; j < 4; ++j) {
        s0 += fabsf(acc0[i][nf][j]);
        s1 += fabsf(acc1[i][nf][j]);
      }
#pragma unroll
  for (int off = 1; off < 64; off <<= 1) {
    s0 += __shfl_xor(s0, off, 64);
    s1 += __shfl_xor(s1, off, 64);
  }
  if (l == 0) { red[w] = s0; red[4 + w] = s1; }
  __syncthreads();
  if (t == 0) {
    partial[((size_t)0 * 16 + b) * 256 + ltm] = red[0] + red[1] + red[2] + red[3];
    partial[((size_t)1 * 16 + b) * 256 + ltm] = red[4] + red[5] + red[6] + red[7];
  }
}

__global__ void norm_reduce_kernel(const float* __restrict__ partial, float* __restrict__ outp)
{
  __shared__ float red[4];
  int t = threadIdx.x;
  float s = 0.f;
  for (int i = t; i < 8192; i += 256) s += partial[i];
#pragma unroll
  for (int off = 1; off < 64; off <<= 1) s += __shfl_xor(s, off, 64);
  if ((t & 63) == 0) red[t >> 6] = s;
  __syncthreads();
  if (t == 0) outp[0] = red[0] + red[1] + red[2] + red[3];
}

// ---------------------------------------------------------------- launch
extern "C" void kernel_launch(void* const* d_in, const int* in_sizes, int n_in,
                              void* d_out, int out_size, void* d_ws, size_t ws_size,
                              hipStream_t stream)
{
  const float* query = (const float*)d_in[0];
  const float* key_  = (const float*)d_in[1];
  const float* value = (const float*)d_in[2];
  const float* sf    = (const float*)d_in[3];
  const float* pos   = (const float*)d_in[4];
  const float* Wq  = (const float*)d_in[5];  const float* bq  = (const float*)d_in[6];
  const float* Wk  = (const float*)d_in[7];  const float* bk  = (const float*)d_in[8];
  const float* Wv  = (const float*)d_in[9];  const float* bv  = (const float*)d_in[10];
  const float* W1  = (const float*)d_in[11]; const float* b1  = (const float*)d_in[12];
  const float* W2  = (const float*)d_in[13]; const float* b2  = (const float*)d_in[14];
  const float* Wqc = (const float*)d_in[15]; const float* bqc = (const float*)d_in[16];
  const float* Wkc = (const float*)d_in[17]; const float* bkc = (const float*)d_in[18];
  float* out = (float*)d_out;

  char* ws = (char*)d_ws;
  size_t off = 0;
  auto alloc = [&](size_t bytes) {
    char* p = ws + off;
    off += (bytes + 255) & ~(size_t)255;
    return p;
  };
  unsigned short* Wf   = (unsigned short*)alloc((size_t)3 * 131072 * 2);
  unsigned short* Ut   = (unsigned short*)alloc((size_t)256 * 128 * 2);
  float* cqck          = (float*)alloc(256 * 4);
  float* Asf           = (float*)alloc(16 * 128 * 4);
  float* Ppos          = (float*)alloc((size_t)2048 * 128 * 4);
  unsigned short* qbf  = (unsigned short*)alloc((size_t)32768 * 128 * 2);
  unsigned short* kbf  = (unsigned short*)alloc((size_t)32768 * 128 * 2);
  unsigned short* vt   = (unsigned short*)alloc((size_t)32768 * 128 * 2);
  unsigned short* qc   = (unsigned short*)alloc((size_t)32768 * 128 * 2);
  unsigned short* kc   = (unsigned short*)alloc((size_t)32768 * 128 * 2);
  float* M2p           = (float*)alloc((size_t)8 * 262144 * 4);
  float* M2t           = (float*)alloc((size_t)262144 * 4);
  float* npartial      = (float*)alloc((size_t)8192 * 4);
  (void)ws_size; (void)in_sizes; (void)n_in; (void)out_size;

  prep_kernel<<<2577, 256, 0, stream>>>(Wq, Wk, Wv, W1, b1, W2, b2, Wqc, bqc, Wkc, bkc,
                                        sf, pos, Wf, Ut, cqck, Asf, Ppos);
  proj_kernel<<<1024, 256, 0, stream>>>(query, Wf,          bq, qbf, kbf, vt, 0);
  proj_kernel<<<1024, 256, 0, stream>>>(key_,  Wf + 131072, bk, qbf, kbf, vt, 1);
  proj_kernel<<<1024, 256, 0, stream>>>(value, Wf + 262144, bv, qbf, kbf, vt, 2);
  qckc_kernel<<<512, 256, 0, stream>>>(Asf, Ppos, Ut, cqck, qc, kc);
  m2_partial_kernel<<<dim3(8, 16), 256, 0, stream>>>(vt, kc, M2p);
  m2_reduce_kernel<<<1024, 256, 0, stream>>>(M2p, M2t);
  attn_kernel<<<512, 256, 0, stream>>>(qbf, kbf, vt, qc, M2t, out);
  norm_kernel<<<4096, 256, 0, stream>>>(qc, kc, npartial);
  norm_reduce_kernel<<<1, 256, 0, stream>>>(npartial, out + (size_t)4194304);
}

// Round 17
// 335.665 us; speedup vs baseline: 1.2569x; 1.0569x over previous
//
#include <hip/hip_runtime.h>
#include <hip/hip_bf16.h>

typedef __attribute__((ext_vector_type(8))) short short8;
typedef __attribute__((ext_vector_type(4))) short short4x;
typedef __attribute__((ext_vector_type(4))) float floatx4;

#define MFMA16(a,b,c) __builtin_amdgcn_mfma_f32_16x16x32_bf16((a),(b),(c),0,0,0)

__device__ __forceinline__ unsigned short f2bf(float f) {
  unsigned int x = __float_as_uint(f);
  return (unsigned short)((x + 0x7fffu + ((x >> 16) & 1u)) >> 16);
}
__device__ __forceinline__ float bf2f(unsigned short s) {
  return __uint_as_float(((unsigned int)s) << 16);
}
__device__ __forceinline__ unsigned short f2bf_cvt(float f) {
  unsigned int r;
  asm("v_cvt_pk_bf16_f32 %0, %1, %1" : "=v"(r) : "v"(f));
  return (unsigned short)r;
}

// ---------------------------------------------------------------- prep
__global__ __launch_bounds__(256)
void prep_kernel(const float* __restrict__ Wq, const float* __restrict__ Wk,
                 const float* __restrict__ Wv, const float* __restrict__ W1,
                 const float* __restrict__ b1, const float* __restrict__ W2,
                 const float* __restrict__ b2, const float* __restrict__ Wqc,
                 const float* __restrict__ bqc, const float* __restrict__ Wkc,
                 const float* __restrict__ bkc, const float* __restrict__ sf,
                 const float* __restrict__ pos,
                 unsigned short* __restrict__ Wf, unsigned short* __restrict__ Ut,
                 float* __restrict__ cqck, float* __restrict__ Asf,
                 float* __restrict__ Ppos)
{
  int blk = blockIdx.x, t = threadIdx.x;
  if (blk < 24) {
    int mat = blk >> 3, cg = blk & 7;
    const float* W = (mat == 0) ? Wq : (mat == 1) ? Wk : Wv;
    int l = t & 63, jp = t >> 6;
    int col = cg * 16 + (l & 15);
    unsigned short* o = Wf + (size_t)mat * 131072 + (size_t)cg * 32 * 512 + l * 8 + jp * 2;
    for (int ks = 0; ks < 32; ++ks) {
      int k = ks * 32 + (l >> 4) * 8 + jp * 2;
      o[ks * 512 + 0] = f2bf(W[(size_t)k * 128 + col]);
      o[ks * 512 + 1] = f2bf(W[(size_t)(k + 1) * 128 + col]);
    }
  } else if (blk >= 384 && blk < 512) {
    int j = blk - 384;
    int k = t & 127;
    const float* Wc = (t < 128) ? Wqc : Wkc;
    float acc = 0.f;
    for (int h = 0; h < 128; ++h) acc += W2[k * 128 + h] * Wc[h * 128 + j];
    Ut[(size_t)((t < 128) ? j : 128 + j) * 128 + k] = f2bf(acc);
  } else if (blk == 512) {
    int j = t & 127;
    const float* Wc = (t < 128) ? Wqc : Wkc;
    const float* bc = (t < 128) ? bqc : bkc;
    float acc = bc[j];
    for (int k = 0; k < 128; ++k) acc += b2[k] * Wc[k * 128 + j];
    cqck[t] = acc;
  } else if (blk > 512 && blk < 529) {
    int b = blk - 513;
    if (t < 128) {
      float acc = 0.f;
      for (int i = 0; i < 64; ++i) acc += sf[b * 64 + i] * W1[i * 128 + t];
      Asf[b * 128 + t] = acc;
    }
  } else if (blk >= 529) {
    int l = blk - 529;
    if (t < 128) {
      float acc = b1[t];
      for (int i = 0; i < 32; ++i) acc += pos[l * 32 + i] * W1[(64 + i) * 128 + t];
      Ppos[l * 128 + t] = acc;
    }
  }
}

// ---------------------------------------------------------------- projections (R13 body, merged launch)
__global__ __launch_bounds__(256)
void proj_kernel(const float* __restrict__ Xq, const float* __restrict__ Xk,
                 const float* __restrict__ Xv, const unsigned short* __restrict__ Wf3,
                 const float* __restrict__ bq, const float* __restrict__ bk,
                 const float* __restrict__ bv,
                 unsigned short* __restrict__ qo, unsigned short* __restrict__ ko,
                 unsigned short* __restrict__ vto)
{
  int which = blockIdx.y;
  const float* X = (which == 0) ? Xq : (which == 1) ? Xk : Xv;
  const unsigned short* Wf = Wf3 + (size_t)which * 131072;
  const float* bias = (which == 0) ? bq : (which == 1) ? bk : bv;

  __shared__ __align__(16) unsigned short X_lds[32 * 1032];   // 66048 B

  int t = threadIdx.x, w = t >> 6, l = t & 63;
  int rowbase = blockIdx.x * 32;
  const int lrow = l & 15, hi = l >> 4;
  const float RS2 = 0.08838834764831845f * 1.4426950408889634f;

#pragma unroll
  for (int r = 0; r < 8; ++r) {
    int row = w * 8 + r;
    const float* src = X + (size_t)(rowbase + row) * 1024 + l * 4;
    unsigned short* dst = &X_lds[row * 1032 + l * 4];
#pragma unroll
    for (int i = 0; i < 4; ++i) {
      float4 v = *(const float4*)(src + i * 256);
      short4x s;
      s[0] = (short)f2bf(v.x); s[1] = (short)f2bf(v.y);
      s[2] = (short)f2bf(v.z); s[3] = (short)f2bf(v.w);
      *(short4x*)(dst + i * 256) = s;
    }
  }
  __syncthreads();

  const unsigned short* wp0 = Wf + (size_t)(w * 2) * 32 * 512 + l * 8;
  const unsigned short* wp1 = Wf + (size_t)(w * 2 + 1) * 32 * 512 + l * 8;
  const int xo0 = lrow * 1032 + hi * 8;
  const int xo1 = (lrow + 16) * 1032 + hi * 8;

  floatx4 acc[2][2];
#pragma unroll
  for (int i = 0; i < 2; ++i)
#pragma unroll
    for (int j = 0; j < 2; ++j) { acc[i][j][0]=0.f; acc[i][j][1]=0.f; acc[i][j][2]=0.f; acc[i][j][3]=0.f; }

#pragma unroll 4
  for (int ks = 0; ks < 32; ++ks) {
    short8 b0 = *(const short8*)(wp0 + ks * 512);
    short8 b1 = *(const short8*)(wp1 + ks * 512);
    short8 a0 = *(const short8*)&X_lds[xo0 + ks * 32];
    short8 a1 = *(const short8*)&X_lds[xo1 + ks * 32];
    acc[0][0] = MFMA16(a0, b0, acc[0][0]);
    acc[0][1] = MFMA16(a0, b1, acc[0][1]);
    acc[1][0] = MFMA16(a1, b0, acc[1][0]);
    acc[1][1] = MFMA16(a1, b1, acc[1][1]);
  }

#pragma unroll
  for (int mf = 0; mf < 2; ++mf)
#pragma unroll
    for (int nf = 0; nf < 2; ++nf) {
      int col = w * 32 + nf * 16 + lrow;
      float bb = bias[col];
#pragma unroll
      for (int j = 0; j < 4; ++j) {
        int grow = rowbase + mf * 16 + hi * 4 + j;
        float v = acc[mf][nf][j] + bb;
        if (which == 0) qo[(size_t)grow * 128 + col] = f2bf(v * RS2);
        else if (which == 1) ko[(size_t)grow * 128 + col] = f2bf(v);
        else {
          int b = grow >> 11, li = grow & 2047;
          vto[((size_t)b * 128 + col) * 2048 + li] = f2bf(v);
        }
      }
    }
}

// ---------------------------------------------------------------- qc / kc
__global__ __launch_bounds__(256)
void qckc_kernel(const float* __restrict__ Asf, const float* __restrict__ Ppos,
                 const unsigned short* __restrict__ Ut, const float* __restrict__ cqck,
                 unsigned short* __restrict__ qc, unsigned short* __restrict__ kc)
{
  __shared__ __align__(16) unsigned short hid[64 * 136];
  int t = threadIdx.x, w = t >> 6, l = t & 63;
  int lbase = blockIdx.x * 64;
  int b = lbase >> 11;
  const int lrow = l & 15, lk = (l >> 4) * 8;
  {
    int r = t >> 2, seg = (t & 3) * 32;
    const float* pp = Ppos + (size_t)((lbase + r) & 2047) * 128 + seg;
    const float* aa = Asf + b * 128 + seg;
    unsigned short* dst = hid + r * 136 + seg;
#pragma unroll
    for (int c = 0; c < 32; c += 4) {
      float4 p4 = *(const float4*)(pp + c);
      float4 a4 = *(const float4*)(aa + c);
      dst[c + 0] = f2bf(fmaxf(p4.x + a4.x, 0.f));
      dst[c + 1] = f2bf(fmaxf(p4.y + a4.y, 0.f));
      dst[c + 2] = f2bf(fmaxf(p4.z + a4.z, 0.f));
      dst[c + 3] = f2bf(fmaxf(p4.w + a4.w, 0.f));
    }
  }
  __syncthreads();
  short8 a[4];
#pragma unroll
  for (int ks = 0; ks < 4; ++ks)
    a[ks] = *(const short8*)&hid[(w * 16 + lrow) * 136 + ks * 32 + lk];
  floatx4 acc[16];
#pragma unroll
  for (int nf = 0; nf < 16; ++nf) { acc[nf][0]=0.f; acc[nf][1]=0.f; acc[nf][2]=0.f; acc[nf][3]=0.f; }
#pragma unroll
  for (int nf = 0; nf < 16; ++nf)
#pragma unroll
    for (int ks = 0; ks < 4; ++ks) {
      short8 bfr = *(const short8*)(Ut + (size_t)(nf * 16 + lrow) * 128 + ks * 32 + lk);
      acc[nf] = MFMA16(a[ks], bfr, acc[nf]);
    }
#pragma unroll
  for (int nf = 0; nf < 16; ++nf) {
    int col = nf * 16 + lrow;
    float bb = cqck[col];
#pragma unroll
    for (int j = 0; j < 4; ++j) {
      int grow = lbase + w * 16 + (l >> 4) * 4 + j;
      float v = acc[nf][j] + bb;
      if (col < 128) qc[(size_t)grow * 128 + col] = f2bf(v);
      else kc[(size_t)grow * 128 + (col - 128)] = f2bf(v);
    }
  }
}

// ---------------------------------------------------------------- M2 partial
__global__ __launch_bounds__(256)
void m2_partial_kernel(const unsigned short* __restrict__ vt,
                       const unsigned short* __restrict__ kc,
                       float* __restrict__ M2p)
{
  __shared__ __align__(16) unsigned short kct[128 * 40];
  int ks = blockIdx.x, b = blockIdx.y;
  int t = threadIdx.x, w = t >> 6, l = t & 63;
  const int lrow = l & 15, lk = (l >> 4) * 8;
  floatx4 acc[2][8];
#pragma unroll
  for (int i = 0; i < 2; ++i)
#pragma unroll
    for (int j = 0; j < 8; ++j) { acc[i][j][0]=0.f; acc[i][j][1]=0.f; acc[i][j][2]=0.f; acc[i][j][3]=0.f; }
  for (int mc = 0; mc < 8; ++mc) {
    int mbase = ks * 256 + mc * 32;
    {
      int mm = t & 31, ib = (t >> 5) * 16;
      const unsigned short* src = kc + ((size_t)b * 2048 + mbase + mm) * 128 + ib;
#pragma unroll
      for (int ii = 0; ii < 16; ++ii) kct[(ib + ii) * 40 + mm] = src[ii];
    }
    __syncthreads();
#pragma unroll
    for (int mf = 0; mf < 2; ++mf) {
      int jrow = w * 32 + mf * 16 + lrow;
      short8 a = *(const short8*)(vt + ((size_t)b * 128 + jrow) * 2048 + mbase + lk);
#pragma unroll
      for (int nf = 0; nf < 8; ++nf) {
        short8 bfr = *(const short8*)&kct[(nf * 16 + lrow) * 40 + lk];
        acc[mf][nf] = MFMA16(a, bfr, acc[mf][nf]);
      }
    }
    __syncthreads();
  }
#pragma unroll
  for (int mf = 0; mf < 2; ++mf)
#pragma unroll
    for (int nf = 0; nf < 8; ++nf)
#pragma unroll
      for (int j = 0; j < 4; ++j) {
        int jr = w * 32 + mf * 16 + (l >> 4) * 4 + j;
        int ic = nf * 16 + lrow;
        M2p[(((size_t)ks * 16 + b) * 128 + jr) * 128 + ic] = acc[mf][nf][j];
      }
}

__global__ void m2_reduce_kernel(const float* __restrict__ M2p, float* __restrict__ M2t)
{
  int idx = blockIdx.x * 256 + threadIdx.x;
  float s = 0.f;
#pragma unroll
  for (int ksp = 0; ksp < 8; ++ksp) s += M2p[(size_t)ksp * 262144 + idx];
  M2t[idx] = s;
}

// ---------------------------------------------------------------- attention
// R16 + (a) per-lane s_run partials: sum-shuffles removed from the loop,
// one 16-lane reduce in the epilogue (rescale is linear so defer-max still
// applies); (b) lazy tile-max: the defer check is per-lane + __any, the
// shuffled exact row max is only computed inside the rare rescale branch.
__global__ __launch_bounds__(256)
void attn_kernel(const unsigned short* __restrict__ qbf, const unsigned short* __restrict__ kbf,
                 const unsigned short* __restrict__ vt, const unsigned short* __restrict__ qc,
                 const float* __restrict__ M2t, float* __restrict__ out)
{
  __shared__ __align__(16) unsigned short K_lds[64 * 136];
  __shared__ __align__(16) unsigned short V_lds[128 * 72];
  __shared__ __align__(16) unsigned short P_lds[4 * 16 * 72];
  int t = threadIdx.x, w = t >> 6, l = t & 63;
  int id = blockIdx.x;
  int xcd = id & 7, seq = id >> 3;
  int b = xcd * 2 + (seq >> 5);
  int lbase = (seq & 31) * 64;
  const int lrow = l & 15, lk = (l >> 4) * 8;

  size_t browq = (size_t)b * 2048 + lbase + w * 16 + lrow;
  short8 aq[4];
#pragma unroll
  for (int ks = 0; ks < 4; ++ks)
    aq[ks] = *(const short8*)(qbf + browq * 128 + ks * 32 + lk);

  float m_run[4] = {-1e30f, -1e30f, -1e30f, -1e30f};
  float s_run[4] = {0.f, 0.f, 0.f, 0.f};   // PER-LANE partial sums
  floatx4 o[8];
#pragma unroll
  for (int nf = 0; nf < 8; ++nf) { o[nf][0]=0.f; o[nf][1]=0.f; o[nf][2]=0.f; o[nf][3]=0.f; }

  int sr = t >> 2, sseg = (t & 3) * 32;
  int vr = t >> 1, vseg = (t & 1) * 32;

  const short8* ksrc0 = (const short8*)(kbf + ((size_t)b * 2048 + sr) * 128 + sseg);
  const short8* vsrc0 = (const short8*)(vt + ((size_t)b * 128 + vr) * 2048 + vseg);

  short8 kr[4], vrg[4];
#pragma unroll
  for (int i = 0; i < 4; ++i) { kr[i] = ksrc0[i]; vrg[i] = vsrc0[i]; }

  for (int kt = 0; kt < 32; ++kt) {
    {
      short8* dst = (short8*)&K_lds[sr * 136 + sseg];
      dst[0] = kr[0]; dst[1] = kr[1]; dst[2] = kr[2]; dst[3] = kr[3];
      short8* vdst = (short8*)&V_lds[vr * 72 + vseg];
      vdst[0] = vrg[0]; vdst[1] = vrg[1]; vdst[2] = vrg[2]; vdst[3] = vrg[3];
    }
    __syncthreads();
    if (kt < 31) {
      const short8* ks2 = ksrc0 + (size_t)(kt + 1) * 1024;
      const short8* vs2 = vsrc0 + (size_t)(kt + 1) * 8;
#pragma unroll
      for (int i = 0; i < 4; ++i) { kr[i] = ks2[i]; vrg[i] = vs2[i]; }
    }
    floatx4 s[4];
    __builtin_amdgcn_s_setprio(1);
#pragma unroll
    for (int cf = 0; cf < 4; ++cf) {
      floatx4 a4; a4[0]=0.f; a4[1]=0.f; a4[2]=0.f; a4[3]=0.f;
#pragma unroll
      for (int ks = 0; ks < 4; ++ks) {
        short8 bfr = *(const short8*)&K_lds[(cf * 16 + lrow) * 136 + ks * 32 + lk];
        a4 = MFMA16(aq[ks], bfr, a4);
      }
      s[cf] = a4;
    }
    __builtin_amdgcn_s_setprio(0);
    // lazy defer-max check: per-lane, no shuffles in the common path
    bool need = false;
#pragma unroll
    for (int cf = 0; cf < 4; ++cf)
#pragma unroll
      for (int j = 0; j < 4; ++j)
        need |= (s[cf][j] > m_run[j] + 8.f);
    if (__any(need)) {
      float tm[4];
#pragma unroll
      for (int j = 0; j < 4; ++j) {
        float m0 = fmaxf(fmaxf(s[0][j], s[1][j]), fmaxf(s[2][j], s[3][j]));
#pragma unroll
        for (int off = 1; off < 16; off <<= 1) m0 = fmaxf(m0, __shfl_xor(m0, off, 64));
        tm[j] = m0;
      }
      float fmul[4];
#pragma unroll
      for (int j = 0; j < 4; ++j) {
        float nm = fmaxf(m_run[j], tm[j]);
        fmul[j] = exp2f(m_run[j] - nm);
        m_run[j] = nm;
        s_run[j] *= fmul[j];
      }
#pragma unroll
      for (int nf = 0; nf < 8; ++nf)
#pragma unroll
        for (int j = 0; j < 4; ++j) o[nf][j] *= fmul[j];
    }
#pragma unroll
    for (int j = 0; j < 4; ++j) {
#pragma unroll
      for (int cf = 0; cf < 4; ++cf) {
        float p = exp2f(s[cf][j] - m_run[j]);
        s[cf][j] = p;
        s_run[j] += p;       // per-lane partial; reduced once in epilogue
      }
    }
    unsigned short* pw = P_lds + w * (16 * 72);
#pragma unroll
    for (int cf = 0; cf < 4; ++cf)
#pragma unroll
      for (int j = 0; j < 4; ++j)
        pw[((l >> 4) * 4 + j) * 72 + cf * 16 + lrow] = f2bf_cvt(s[cf][j]);
    __builtin_amdgcn_s_setprio(1);
#pragma unroll
    for (int kf = 0; kf < 2; ++kf) {
      short8 ap = *(const short8*)&pw[lrow * 72 + kf * 32 + lk];
#pragma unroll
      for (int nf = 0; nf < 8; ++nf) {
        short8 bv = *(const short8*)&V_lds[(nf * 16 + lrow) * 72 + kf * 32 + lk];
        o[nf] = MFMA16(ap, bv, o[nf]);
      }
    }
    __builtin_amdgcn_s_setprio(0);
    __syncthreads();
  }
  // epilogue: reduce the per-lane partials once, then normalize
  float inv[4];
#pragma unroll
  for (int j = 0; j < 4; ++j) {
#pragma unroll
    for (int off = 1; off < 16; off <<= 1) s_run[j] += __shfl_xor(s_run[j], off, 64);
    inv[j] = 1.f / s_run[j];
  }
#pragma unroll
  for (int nf = 0; nf < 8; ++nf)
#pragma unroll
    for (int j = 0; j < 4; ++j) o[nf][j] *= inv[j];
#pragma unroll
  for (int ks = 0; ks < 4; ++ks) {
    short8 aqc = *(const short8*)(qc + browq * 128 + ks * 32 + lk);
#pragma unroll
    for (int nf = 0; nf < 8; ++nf) {
      const float* mp = M2t + ((size_t)b * 128 + nf * 16 + lrow) * 128 + ks * 32 + lk;
      float4 m0 = *(const float4*)(mp);
      float4 m1 = *(const float4*)(mp + 4);
      short8 bm;
      bm[0]=(short)f2bf(m0.x); bm[1]=(short)f2bf(m0.y); bm[2]=(short)f2bf(m0.z); bm[3]=(short)f2bf(m0.w);
      bm[4]=(short)f2bf(m1.x); bm[5]=(short)f2bf(m1.y); bm[6]=(short)f2bf(m1.z); bm[7]=(short)f2bf(m1.w);
      o[nf] = MFMA16(aqc, bm, o[nf]);
    }
  }
#pragma unroll
  for (int nf = 0; nf < 8; ++nf)
#pragma unroll
    for (int j = 0; j < 4; ++j) {
      int grow = lbase + w * 16 + (l >> 4) * 4 + j;
      out[((size_t)b * 2048 + grow) * 128 + nf * 16 + lrow] = o[nf][j];
    }
}

// ---------------------------------------------------------------- norm (R16 form, XCD swizzle)
__global__ __launch_bounds__(256)
void norm_kernel(const unsigned short* __restrict__ qc, const unsigned short* __restrict__ kc,
                 float* __restrict__ partial)
{
  __shared__ __align__(16) unsigned short T1[129 * 136];
  __shared__ __align__(16) unsigned short T2[129 * 136];
  __shared__ float red[8];
  int t = threadIdx.x, w = t >> 6, l = t & 63;
  int id = blockIdx.x;
  int xcd = id & 7, seq = id >> 3;
  int b = xcd * 2 + (seq >> 8);
  int ltm = seq & 255;
  int lt = ltm >> 4, mt = ltm & 15;
  const int lrow = l & 15, lk = (l >> 4) * 8;
  {
    int r = t >> 1, half = (t & 1) * 64;
    const unsigned short* asrc = qc + ((size_t)b * 2048 + lt * 128 + r) * 128 + half;
    const unsigned short* bsrc = kc + ((size_t)b * 2048 + mt * 128 + r) * 128 + half;
    unsigned short* adst = T1 + r * 136 + half;
    unsigned short* bdst = T2 + r * 136 + half;
#pragma unroll
    for (int c = 0; c < 64; c += 8) {
      *(short8*)(adst + c) = *(const short8*)(asrc + c);
      *(short8*)(bdst + c) = *(const short8*)(bsrc + c);
    }
    if (t < 16) {
      int gr = lt * 128 + 128; if (gr > 2047) gr = 2047;
      *(short8*)(T1 + 128 * 136 + t * 8) =
          *(const short8*)(qc + ((size_t)b * 2048 + gr) * 128 + t * 8);
    } else if (t < 32) {
      int c = (t - 16) * 8;
      int gr = mt * 128 + 128; if (gr > 2047) gr = 2047;
      *(short8*)(T2 + 128 * 136 + c) =
          *(const short8*)(kc + ((size_t)b * 2048 + gr) * 128 + c);
    }
  }
  __syncthreads();
  floatx4 acc0[2][8], acc1[2][8];
#pragma unroll
  for (int i = 0; i < 2; ++i)
#pragma unroll
    for (int j = 0; j < 8; ++j) {
      acc0[i][j][0]=0.f; acc0[i][j][1]=0.f; acc0[i][j][2]=0.f; acc0[i][j][3]=0.f;
      acc1[i][j][0]=0.f; acc1[i][j][1]=0.f; acc1[i][j][2]=0.f; acc1[i][j][3]=0.f;
    }
#pragma unroll
  for (int ks = 0; ks < 4; ++ks) {
    int off = ks * 32 + lk;
    short8 ad[2], cd[2];
#pragma unroll
    for (int mf = 0; mf < 2; ++mf) {
      int r = w * 32 + mf * 16 + lrow;
      short8 x1 = *(const short8*)&T1[r * 136 + off];
      short8 y1 = *(const short8*)&T1[(r + 1) * 136 + off];
      short8 x2 = *(const short8*)&T2[r * 136 + off];
      short8 y2 = *(const short8*)&T2[(r + 1) * 136 + off];
      short8 d1, d2;
#pragma unroll
      for (int ii = 0; ii < 8; ++ii) {
        d1[ii] = (short)f2bf(bf2f((unsigned short)y1[ii]) - bf2f((unsigned short)x1[ii]));
        d2[ii] = (short)f2bf(bf2f((unsigned short)y2[ii]) - bf2f((unsigned short)x2[ii]));
      }
      ad[mf] = d1; cd[mf] = d2;
    }
#pragma unroll
    for (int nf = 0; nf < 8; ++nf) {
      short8 bk = *(const short8*)&T2[(nf * 16 + lrow) * 136 + off];
      short8 bq = *(const short8*)&T1[(nf * 16 + lrow) * 136 + off];
      acc0[0][nf] = MFMA16(ad[0], bk, acc0[0][nf]);
      acc0[1][nf] = MFMA16(ad[1], bk, acc0[1][nf]);
      acc1[0][nf] = MFMA16(cd[0], bq, acc1[0][nf]);
      acc1[1][nf] = MFMA16(cd[1], bq, acc1[1][nf]);
    }
  }
  float s0 = 0.f, s1 = 0.f;
#pragma unroll
  for (int i = 0; i < 2; ++i)
#pragma unroll
    for (int nf = 0; nf < 8; ++nf)
#pragma unroll
      for (int j = 0; j < 4; ++j) {
        s0 += fabsf(acc0[i][nf][j]);
        s1 += fabsf(acc1[i][nf][j]);
      }
#pragma unroll
  for (int off = 1; off < 64; off <<= 1) {
    s0 += __shfl_xor(s0, off, 64);
    s1 += __shfl_xor(s1, off, 64);
  }
  if (l == 0) { red[w] = s0; red[4 + w] = s1; }
  __syncthreads();
  if (t == 0) {
    partial[((size_t)0 * 16 + b) * 256 + ltm] = red[0] + red[1] + red[2] + red[3];
    partial[((size_t)1 * 16 + b) * 256 + ltm] = red[4] + red[5] + red[6] + red[7];
  }
}

__global__ void norm_reduce_kernel(const float* __restrict__ partial, float* __restrict__ outp)
{
  __shared__ float red[4];
  int t = threadIdx.x;
  float s = 0.f;
  for (int i = t; i < 8192; i += 256) s += partial[i];
#pragma unroll
  for (int off = 1; off < 64; off <<= 1) s += __shfl_xor(s, off, 64);
  if ((t & 63) == 0) red[t >> 6] = s;
  __syncthreads();
  if (t == 0) outp[0] = red[0] + red[1] + red[2] + red[3];
}

// ---------------------------------------------------------------- launch
extern "C" void kernel_launch(void* const* d_in, const int* in_sizes, int n_in,
                              void* d_out, int out_size, void* d_ws, size_t ws_size,
                              hipStream_t stream)
{
  const float* query = (const float*)d_in[0];
  const float* key_  = (const float*)d_in[1];
  const float* value = (const float*)d_in[2];
  const float* sf    = (const float*)d_in[3];
  const float* pos   = (const float*)d_in[4];
  const float* Wq  = (const float*)d_in[5];  const float* bq  = (const float*)d_in[6];
  const float* Wk  = (const float*)d_in[7];  const float* bk  = (const float*)d_in[8];
  const float* Wv  = (const float*)d_in[9];  const float* bv  = (const float*)d_in[10];
  const float* W1  = (const float*)d_in[11]; const float* b1  = (const float*)d_in[12];
  const float* W2  = (const float*)d_in[13]; const float* b2  = (const float*)d_in[14];
  const float* Wqc = (const float*)d_in[15]; const float* bqc = (const float*)d_in[16];
  const float* Wkc = (const float*)d_in[17]; const float* bkc = (const float*)d_in[18];
  float* out = (float*)d_out;

  char* ws = (char*)d_ws;
  size_t off = 0;
  auto alloc = [&](size_t bytes) {
    char* p = ws + off;
    off += (bytes + 255) & ~(size_t)255;
    return p;
  };
  unsigned short* Wf   = (unsigned short*)alloc((size_t)3 * 131072 * 2);
  unsigned short* Ut   = (unsigned short*)alloc((size_t)256 * 128 * 2);
  float* cqck          = (float*)alloc(256 * 4);
  float* Asf           = (float*)alloc(16 * 128 * 4);
  float* Ppos          = (float*)alloc((size_t)2048 * 128 * 4);
  unsigned short* qbf  = (unsigned short*)alloc((size_t)32768 * 128 * 2);
  unsigned short* kbf  = (unsigned short*)alloc((size_t)32768 * 128 * 2);
  unsigned short* vt   = (unsigned short*)alloc((size_t)32768 * 128 * 2);
  unsigned short* qc   = (unsigned short*)alloc((size_t)32768 * 128 * 2);
  unsigned short* kc   = (unsigned short*)alloc((size_t)32768 * 128 * 2);
  float* M2p           = (float*)alloc((size_t)8 * 262144 * 4);
  float* M2t           = (float*)alloc((size_t)262144 * 4);
  float* npartial      = (float*)alloc((size_t)8192 * 4);
  (void)ws_size; (void)in_sizes; (void)n_in; (void)out_size;

  prep_kernel<<<2577, 256, 0, stream>>>(Wq, Wk, Wv, W1, b1, W2, b2, Wqc, bqc, Wkc, bkc,
                                        sf, pos, Wf, Ut, cqck, Asf, Ppos);
  proj_kernel<<<dim3(1024, 3), 256, 0, stream>>>(query, key_, value, Wf, bq, bk, bv,
                                                 qbf, kbf, vt);
  qckc_kernel<<<512, 256, 0, stream>>>(Asf, Ppos, Ut, cqck, qc, kc);
  m2_partial_kernel<<<dim3(8, 16), 256, 0, stream>>>(vt, kc, M2p);
  m2_reduce_kernel<<<1024, 256, 0, stream>>>(M2p, M2t);
  attn_kernel<<<512, 256, 0, stream>>>(qbf, kbf, vt, qc, M2t, out);
  norm_kernel<<<4096, 256, 0, stream>>>(qc, kc, npartial);
  norm_reduce_kernel<<<1, 256, 0, stream>>>(npartial, out + (size_t)4194304);
}

// Round 18
// 332.046 us; speedup vs baseline: 1.2706x; 1.0109x over previous
//
#include <hip/hip_runtime.h>
#include <hip/hip_bf16.h>

typedef __attribute__((ext_vector_type(8))) short short8;
typedef __attribute__((ext_vector_type(4))) short short4x;
typedef __attribute__((ext_vector_type(4))) float floatx4;

#define MFMA16(a,b,c) __builtin_amdgcn_mfma_f32_16x16x32_bf16((a),(b),(c),0,0,0)

__device__ __forceinline__ unsigned short f2bf(float f) {
  unsigned int x = __float_as_uint(f);
  return (unsigned short)((x + 0x7fffu + ((x >> 16) & 1u)) >> 16);
}
__device__ __forceinline__ float bf2f(unsigned short s) {
  return __uint_as_float(((unsigned int)s) << 16);
}
__device__ __forceinline__ unsigned short f2bf_cvt(float f) {
  unsigned int r;
  asm("v_cvt_pk_bf16_f32 %0, %1, %1" : "=v"(r) : "v"(f));
  return (unsigned short)r;
}

// ---------------------------------------------------------------- prep
__global__ __launch_bounds__(256)
void prep_kernel(const float* __restrict__ Wq, const float* __restrict__ Wk,
                 const float* __restrict__ Wv, const float* __restrict__ W1,
                 const float* __restrict__ b1, const float* __restrict__ W2,
                 const float* __restrict__ b2, const float* __restrict__ Wqc,
                 const float* __restrict__ bqc, const float* __restrict__ Wkc,
                 const float* __restrict__ bkc, const float* __restrict__ sf,
                 const float* __restrict__ pos,
                 unsigned short* __restrict__ Wf, unsigned short* __restrict__ Ut,
                 float* __restrict__ cqck, float* __restrict__ Asf,
                 float* __restrict__ Ppos)
{
  int blk = blockIdx.x, t = threadIdx.x;
  if (blk < 24) {
    int mat = blk >> 3, cg = blk & 7;
    const float* W = (mat == 0) ? Wq : (mat == 1) ? Wk : Wv;
    int l = t & 63, jp = t >> 6;
    int col = cg * 16 + (l & 15);
    unsigned short* o = Wf + (size_t)mat * 131072 + (size_t)cg * 32 * 512 + l * 8 + jp * 2;
    for (int ks = 0; ks < 32; ++ks) {
      int k = ks * 32 + (l >> 4) * 8 + jp * 2;
      o[ks * 512 + 0] = f2bf(W[(size_t)k * 128 + col]);
      o[ks * 512 + 1] = f2bf(W[(size_t)(k + 1) * 128 + col]);
    }
  } else if (blk >= 384 && blk < 512) {
    int j = blk - 384;
    int k = t & 127;
    const float* Wc = (t < 128) ? Wqc : Wkc;
    float acc = 0.f;
    for (int h = 0; h < 128; ++h) acc += W2[k * 128 + h] * Wc[h * 128 + j];
    Ut[(size_t)((t < 128) ? j : 128 + j) * 128 + k] = f2bf(acc);
  } else if (blk == 512) {
    int j = t & 127;
    const float* Wc = (t < 128) ? Wqc : Wkc;
    const float* bc = (t < 128) ? bqc : bkc;
    float acc = bc[j];
    for (int k = 0; k < 128; ++k) acc += b2[k] * Wc[k * 128 + j];
    cqck[t] = acc;
  } else if (blk > 512 && blk < 529) {
    int b = blk - 513;
    if (t < 128) {
      float acc = 0.f;
      for (int i = 0; i < 64; ++i) acc += sf[b * 64 + i] * W1[i * 128 + t];
      Asf[b * 128 + t] = acc;
    }
  } else if (blk >= 529) {
    int l = blk - 529;
    if (t < 128) {
      float acc = b1[t];
      for (int i = 0; i < 32; ++i) acc += pos[l * 32 + i] * W1[(64 + i) * 128 + t];
      Ppos[l * 128 + t] = acc;
    }
  }
}

// ---------------------------------------------------------------- projections
// R13 body halved to 16 rows/block: X_lds = 16 x 1032 bf16 = 33KB ->
// 4 blocks/CU (16 waves). More independent stage phases resident per CU so
// block A's compute overlaps block B's stage burst (load-issue duty cycle up).
__global__ __launch_bounds__(256)
void proj_kernel(const float* __restrict__ Xq, const float* __restrict__ Xk,
                 const float* __restrict__ Xv, const unsigned short* __restrict__ Wf3,
                 const float* __restrict__ bq, const float* __restrict__ bk,
                 const float* __restrict__ bv,
                 unsigned short* __restrict__ qo, unsigned short* __restrict__ ko,
                 unsigned short* __restrict__ vto)
{
  int which = blockIdx.y;
  const float* X = (which == 0) ? Xq : (which == 1) ? Xk : Xv;
  const unsigned short* Wf = Wf3 + (size_t)which * 131072;
  const float* bias = (which == 0) ? bq : (which == 1) ? bk : bv;

  __shared__ __align__(16) unsigned short X_lds[16 * 1032];   // 33024 B

  int t = threadIdx.x, w = t >> 6, l = t & 63;
  int rowbase = blockIdx.x * 16;
  const int lrow = l & 15, hi = l >> 4;
  const float RS2 = 0.08838834764831845f * 1.4426950408889634f;

#pragma unroll
  for (int r = 0; r < 4; ++r) {
    int row = w * 4 + r;
    const float* src = X + (size_t)(rowbase + row) * 1024 + l * 4;
    unsigned short* dst = &X_lds[row * 1032 + l * 4];
#pragma unroll
    for (int i = 0; i < 4; ++i) {
      float4 v = *(const float4*)(src + i * 256);
      short4x s;
      s[0] = (short)f2bf(v.x); s[1] = (short)f2bf(v.y);
      s[2] = (short)f2bf(v.z); s[3] = (short)f2bf(v.w);
      *(short4x*)(dst + i * 256) = s;
    }
  }
  __syncthreads();

  const unsigned short* wp0 = Wf + (size_t)(w * 2) * 32 * 512 + l * 8;
  const unsigned short* wp1 = Wf + (size_t)(w * 2 + 1) * 32 * 512 + l * 8;
  const int xo0 = lrow * 1032 + hi * 8;

  floatx4 acc0, acc1;
  acc0[0]=0.f; acc0[1]=0.f; acc0[2]=0.f; acc0[3]=0.f;
  acc1[0]=0.f; acc1[1]=0.f; acc1[2]=0.f; acc1[3]=0.f;

#pragma unroll 4
  for (int ks = 0; ks < 32; ++ks) {
    short8 b0 = *(const short8*)(wp0 + ks * 512);
    short8 b1 = *(const short8*)(wp1 + ks * 512);
    short8 a0 = *(const short8*)&X_lds[xo0 + ks * 32];
    acc0 = MFMA16(a0, b0, acc0);
    acc1 = MFMA16(a0, b1, acc1);
  }

#pragma unroll
  for (int nf = 0; nf < 2; ++nf) {
    int col = w * 32 + nf * 16 + lrow;
    float bb = bias[col];
    floatx4 av = (nf == 0) ? acc0 : acc1;
#pragma unroll
    for (int j = 0; j < 4; ++j) {
      int grow = rowbase + hi * 4 + j;
      float v = av[j] + bb;
      if (which == 0) qo[(size_t)grow * 128 + col] = f2bf(v * RS2);
      else if (which == 1) ko[(size_t)grow * 128 + col] = f2bf(v);
      else {
        int b = grow >> 11, li = grow & 2047;
        vto[((size_t)b * 128 + col) * 2048 + li] = f2bf(v);
      }
    }
  }
}

// ---------------------------------------------------------------- qc / kc
__global__ __launch_bounds__(256)
void qckc_kernel(const float* __restrict__ Asf, const float* __restrict__ Ppos,
                 const unsigned short* __restrict__ Ut, const float* __restrict__ cqck,
                 unsigned short* __restrict__ qc, unsigned short* __restrict__ kc)
{
  __shared__ __align__(16) unsigned short hid[64 * 136];
  int t = threadIdx.x, w = t >> 6, l = t & 63;
  int lbase = blockIdx.x * 64;
  int b = lbase >> 11;
  const int lrow = l & 15, lk = (l >> 4) * 8;
  {
    int r = t >> 2, seg = (t & 3) * 32;
    const float* pp = Ppos + (size_t)((lbase + r) & 2047) * 128 + seg;
    const float* aa = Asf + b * 128 + seg;
    unsigned short* dst = hid + r * 136 + seg;
#pragma unroll
    for (int c = 0; c < 32; c += 4) {
      float4 p4 = *(const float4*)(pp + c);
      float4 a4 = *(const float4*)(aa + c);
      dst[c + 0] = f2bf(fmaxf(p4.x + a4.x, 0.f));
      dst[c + 1] = f2bf(fmaxf(p4.y + a4.y, 0.f));
      dst[c + 2] = f2bf(fmaxf(p4.z + a4.z, 0.f));
      dst[c + 3] = f2bf(fmaxf(p4.w + a4.w, 0.f));
    }
  }
  __syncthreads();
  short8 a[4];
#pragma unroll
  for (int ks = 0; ks < 4; ++ks)
    a[ks] = *(const short8*)&hid[(w * 16 + lrow) * 136 + ks * 32 + lk];
  floatx4 acc[16];
#pragma unroll
  for (int nf = 0; nf < 16; ++nf) { acc[nf][0]=0.f; acc[nf][1]=0.f; acc[nf][2]=0.f; acc[nf][3]=0.f; }
#pragma unroll
  for (int nf = 0; nf < 16; ++nf)
#pragma unroll
    for (int ks = 0; ks < 4; ++ks) {
      short8 bfr = *(const short8*)(Ut + (size_t)(nf * 16 + lrow) * 128 + ks * 32 + lk);
      acc[nf] = MFMA16(a[ks], bfr, acc[nf]);
    }
#pragma unroll
  for (int nf = 0; nf < 16; ++nf) {
    int col = nf * 16 + lrow;
    float bb = cqck[col];
#pragma unroll
    for (int j = 0; j < 4; ++j) {
      int grow = lbase + w * 16 + (l >> 4) * 4 + j;
      float v = acc[nf][j] + bb;
      if (col < 128) qc[(size_t)grow * 128 + col] = f2bf(v);
      else kc[(size_t)grow * 128 + (col - 128)] = f2bf(v);
    }
  }
}

// ---------------------------------------------------------------- M2 partial
__global__ __launch_bounds__(256)
void m2_partial_kernel(const unsigned short* __restrict__ vt,
                       const unsigned short* __restrict__ kc,
                       float* __restrict__ M2p)
{
  __shared__ __align__(16) unsigned short kct[128 * 40];
  int ks = blockIdx.x, b = blockIdx.y;
  int t = threadIdx.x, w = t >> 6, l = t & 63;
  const int lrow = l & 15, lk = (l >> 4) * 8;
  floatx4 acc[2][8];
#pragma unroll
  for (int i = 0; i < 2; ++i)
#pragma unroll
    for (int j = 0; j < 8; ++j) { acc[i][j][0]=0.f; acc[i][j][1]=0.f; acc[i][j][2]=0.f; acc[i][j][3]=0.f; }
  for (int mc = 0; mc < 8; ++mc) {
    int mbase = ks * 256 + mc * 32;
    {
      int mm = t & 31, ib = (t >> 5) * 16;
      const unsigned short* src = kc + ((size_t)b * 2048 + mbase + mm) * 128 + ib;
#pragma unroll
      for (int ii = 0; ii < 16; ++ii) kct[(ib + ii) * 40 + mm] = src[ii];
    }
    __syncthreads();
#pragma unroll
    for (int mf = 0; mf < 2; ++mf) {
      int jrow = w * 32 + mf * 16 + lrow;
      short8 a = *(const short8*)(vt + ((size_t)b * 128 + jrow) * 2048 + mbase + lk);
#pragma unroll
      for (int nf = 0; nf < 8; ++nf) {
        short8 bfr = *(const short8*)&kct[(nf * 16 + lrow) * 40 + lk];
        acc[mf][nf] = MFMA16(a, bfr, acc[mf][nf]);
      }
    }
    __syncthreads();
  }
#pragma unroll
  for (int mf = 0; mf < 2; ++mf)
#pragma unroll
    for (int nf = 0; nf < 8; ++nf)
#pragma unroll
      for (int j = 0; j < 4; ++j) {
        int jr = w * 32 + mf * 16 + (l >> 4) * 4 + j;
        int ic = nf * 16 + lrow;
        M2p[(((size_t)ks * 16 + b) * 128 + jr) * 128 + ic] = acc[mf][nf][j];
      }
}

__global__ void m2_reduce_kernel(const float* __restrict__ M2p, float* __restrict__ M2t)
{
  int idx = blockIdx.x * 256 + threadIdx.x;
  float s = 0.f;
#pragma unroll
  for (int ksp = 0; ksp < 8; ++ksp) s += M2p[(size_t)ksp * 262144 + idx];
  M2t[idx] = s;
}

// ---------------------------------------------------------------- attention (R17 form)
__global__ __launch_bounds__(256)
void attn_kernel(const unsigned short* __restrict__ qbf, const unsigned short* __restrict__ kbf,
                 const unsigned short* __restrict__ vt, const unsigned short* __restrict__ qc,
                 const float* __restrict__ M2t, float* __restrict__ out)
{
  __shared__ __align__(16) unsigned short K_lds[64 * 136];
  __shared__ __align__(16) unsigned short V_lds[128 * 72];
  __shared__ __align__(16) unsigned short P_lds[4 * 16 * 72];
  int t = threadIdx.x, w = t >> 6, l = t & 63;
  int id = blockIdx.x;
  int xcd = id & 7, seq = id >> 3;
  int b = xcd * 2 + (seq >> 5);
  int lbase = (seq & 31) * 64;
  const int lrow = l & 15, lk = (l >> 4) * 8;

  size_t browq = (size_t)b * 2048 + lbase + w * 16 + lrow;
  short8 aq[4];
#pragma unroll
  for (int ks = 0; ks < 4; ++ks)
    aq[ks] = *(const short8*)(qbf + browq * 128 + ks * 32 + lk);

  float m_run[4] = {-1e30f, -1e30f, -1e30f, -1e30f};
  float s_run[4] = {0.f, 0.f, 0.f, 0.f};   // per-lane partial sums
  floatx4 o[8];
#pragma unroll
  for (int nf = 0; nf < 8; ++nf) { o[nf][0]=0.f; o[nf][1]=0.f; o[nf][2]=0.f; o[nf][3]=0.f; }

  int sr = t >> 2, sseg = (t & 3) * 32;
  int vr = t >> 1, vseg = (t & 1) * 32;

  const short8* ksrc0 = (const short8*)(kbf + ((size_t)b * 2048 + sr) * 128 + sseg);
  const short8* vsrc0 = (const short8*)(vt + ((size_t)b * 128 + vr) * 2048 + vseg);

  short8 kr[4], vrg[4];
#pragma unroll
  for (int i = 0; i < 4; ++i) { kr[i] = ksrc0[i]; vrg[i] = vsrc0[i]; }

  for (int kt = 0; kt < 32; ++kt) {
    {
      short8* dst = (short8*)&K_lds[sr * 136 + sseg];
      dst[0] = kr[0]; dst[1] = kr[1]; dst[2] = kr[2]; dst[3] = kr[3];
      short8* vdst = (short8*)&V_lds[vr * 72 + vseg];
      vdst[0] = vrg[0]; vdst[1] = vrg[1]; vdst[2] = vrg[2]; vdst[3] = vrg[3];
    }
    __syncthreads();
    if (kt < 31) {
      const short8* ks2 = ksrc0 + (size_t)(kt + 1) * 1024;
      const short8* vs2 = vsrc0 + (size_t)(kt + 1) * 8;
#pragma unroll
      for (int i = 0; i < 4; ++i) { kr[i] = ks2[i]; vrg[i] = vs2[i]; }
    }
    floatx4 s[4];
    __builtin_amdgcn_s_setprio(1);
#pragma unroll
    for (int cf = 0; cf < 4; ++cf) {
      floatx4 a4; a4[0]=0.f; a4[1]=0.f; a4[2]=0.f; a4[3]=0.f;
#pragma unroll
      for (int ks = 0; ks < 4; ++ks) {
        short8 bfr = *(const short8*)&K_lds[(cf * 16 + lrow) * 136 + ks * 32 + lk];
        a4 = MFMA16(aq[ks], bfr, a4);
      }
      s[cf] = a4;
    }
    __builtin_amdgcn_s_setprio(0);
    bool need = false;
#pragma unroll
    for (int cf = 0; cf < 4; ++cf)
#pragma unroll
      for (int j = 0; j < 4; ++j)
        need |= (s[cf][j] > m_run[j] + 8.f);
    if (__any(need)) {
      float tm[4];
#pragma unroll
      for (int j = 0; j < 4; ++j) {
        float m0 = fmaxf(fmaxf(s[0][j], s[1][j]), fmaxf(s[2][j], s[3][j]));
#pragma unroll
        for (int off = 1; off < 16; off <<= 1) m0 = fmaxf(m0, __shfl_xor(m0, off, 64));
        tm[j] = m0;
      }
      float fmul[4];
#pragma unroll
      for (int j = 0; j < 4; ++j) {
        float nm = fmaxf(m_run[j], tm[j]);
        fmul[j] = exp2f(m_run[j] - nm);
        m_run[j] = nm;
        s_run[j] *= fmul[j];
      }
#pragma unroll
      for (int nf = 0; nf < 8; ++nf)
#pragma unroll
        for (int j = 0; j < 4; ++j) o[nf][j] *= fmul[j];
    }
#pragma unroll
    for (int j = 0; j < 4; ++j) {
#pragma unroll
      for (int cf = 0; cf < 4; ++cf) {
        float p = exp2f(s[cf][j] - m_run[j]);
        s[cf][j] = p;
        s_run[j] += p;
      }
    }
    unsigned short* pw = P_lds + w * (16 * 72);
#pragma unroll
    for (int cf = 0; cf < 4; ++cf)
#pragma unroll
      for (int j = 0; j < 4; ++j)
        pw[((l >> 4) * 4 + j) * 72 + cf * 16 + lrow] = f2bf_cvt(s[cf][j]);
    __builtin_amdgcn_s_setprio(1);
#pragma unroll
    for (int kf = 0; kf < 2; ++kf) {
      short8 ap = *(const short8*)&pw[lrow * 72 + kf * 32 + lk];
#pragma unroll
      for (int nf = 0; nf < 8; ++nf) {
        short8 bv = *(const short8*)&V_lds[(nf * 16 + lrow) * 72 + kf * 32 + lk];
        o[nf] = MFMA16(ap, bv, o[nf]);
      }
    }
    __builtin_amdgcn_s_setprio(0);
    __syncthreads();
  }
  float inv[4];
#pragma unroll
  for (int j = 0; j < 4; ++j) {
#pragma unroll
    for (int off = 1; off < 16; off <<= 1) s_run[j] += __shfl_xor(s_run[j], off, 64);
    inv[j] = 1.f / s_run[j];
  }
#pragma unroll
  for (int nf = 0; nf < 8; ++nf)
#pragma unroll
    for (int j = 0; j < 4; ++j) o[nf][j] *= inv[j];
#pragma unroll
  for (int ks = 0; ks < 4; ++ks) {
    short8 aqc = *(const short8*)(qc + browq * 128 + ks * 32 + lk);
#pragma unroll
    for (int nf = 0; nf < 8; ++nf) {
      const float* mp = M2t + ((size_t)b * 128 + nf * 16 + lrow) * 128 + ks * 32 + lk;
      float4 m0 = *(const float4*)(mp);
      float4 m1 = *(const float4*)(mp + 4);
      short8 bm;
      bm[0]=(short)f2bf(m0.x); bm[1]=(short)f2bf(m0.y); bm[2]=(short)f2bf(m0.z); bm[3]=(short)f2bf(m0.w);
      bm[4]=(short)f2bf(m1.x); bm[5]=(short)f2bf(m1.y); bm[6]=(short)f2bf(m1.z); bm[7]=(short)f2bf(m1.w);
      o[nf] = MFMA16(aqc, bm, o[nf]);
    }
  }
#pragma unroll
  for (int nf = 0; nf < 8; ++nf)
#pragma unroll
    for (int j = 0; j < 4; ++j) {
      int grow = lbase + w * 16 + (l >> 4) * 4 + j;
      out[((size_t)b * 2048 + grow) * 128 + nf * 16 + lrow] = o[nf][j];
    }
}

// ---------------------------------------------------------------- norm (R17 form)
__global__ __launch_bounds__(256)
void norm_kernel(const unsigned short* __restrict__ qc, const unsigned short* __restrict__ kc,
                 float* __restrict__ partial)
{
  __shared__ __align__(16) unsigned short T1[129 * 136];
  __shared__ __align__(16) unsigned short T2[129 * 136];
  __shared__ float red[8];
  int t = threadIdx.x, w = t >> 6, l = t & 63;
  int id = blockIdx.x;
  int xcd = id & 7, seq = id >> 3;
  int b = xcd * 2 + (seq >> 8);
  int ltm = seq & 255;
  int lt = ltm >> 4, mt = ltm & 15;
  const int lrow = l & 15, lk = (l >> 4) * 8;
  {
    int r = t >> 1, half = (t & 1) * 64;
    const unsigned short* asrc = qc + ((size_t)b * 2048 + lt * 128 + r) * 128 + half;
    const unsigned short* bsrc = kc + ((size_t)b * 2048 + mt * 128 + r) * 128 + half;
    unsigned short* adst = T1 + r * 136 + half;
    unsigned short* bdst = T2 + r * 136 + half;
#pragma unroll
    for (int c = 0; c < 64; c += 8) {
      *(short8*)(adst + c) = *(const short8*)(asrc + c);
      *(short8*)(bdst + c) = *(const short8*)(bsrc + c);
    }
    if (t < 16) {
      int gr = lt * 128 + 128; if (gr > 2047) gr = 2047;
      *(short8*)(T1 + 128 * 136 + t * 8) =
          *(const short8*)(qc + ((size_t)b * 2048 + gr) * 128 + t * 8);
    } else if (t < 32) {
      int c = (t - 16) * 8;
      int gr = mt * 128 + 128; if (gr > 2047) gr = 2047;
      *(short8*)(T2 + 128 * 136 + c) =
          *(const short8*)(kc + ((size_t)b * 2048 + gr) * 128 + c);
    }
  }
  __syncthreads();
  floatx4 acc0[2][8], acc1[2][8];
#pragma unroll
  for (int i = 0; i < 2; ++i)
#pragma unroll
    for (int j = 0; j < 8; ++j) {
      acc0[i][j][0]=0.f; acc0[i][j][1]=0.f; acc0[i][j][2]=0.f; acc0[i][j][3]=0.f;
      acc1[i][j][0]=0.f; acc1[i][j][1]=0.f; acc1[i][j][2]=0.f; acc1[i][j][3]=0.f;
    }
#pragma unroll
  for (int ks = 0; ks < 4; ++ks) {
    int off = ks * 32 + lk;
    short8 ad[2], cd[2];
#pragma unroll
    for (int mf = 0; mf < 2; ++mf) {
      int r = w * 32 + mf * 16 + lrow;
      short8 x1 = *(const short8*)&T1[r * 136 + off];
      short8 y1 = *(const short8*)&T1[(r + 1) * 136 + off];
      short8 x2 = *(const short8*)&T2[r * 136 + off];
      short8 y2 = *(const short8*)&T2[(r + 1) * 136 + off];
      short8 d1, d2;
#pragma unroll
      for (int ii = 0; ii < 8; ++ii) {
        d1[ii] = (short)f2bf(bf2f((unsigned short)y1[ii]) - bf2f((unsigned short)x1[ii]));
        d2[ii] = (short)f2bf(bf2f((unsigned short)y2[ii]) - bf2f((unsigned short)x2[ii]));
      }
      ad[mf] = d1; cd[mf] = d2;
    }
#pragma unroll
    for (int nf = 0; nf < 8; ++nf) {
      short8 bk = *(const short8*)&T2[(nf * 16 + lrow) * 136 + off];
      short8 bq = *(const short8*)&T1[(nf * 16 + lrow) * 136 + off];
      acc0[0][nf] = MFMA16(ad[0], bk, acc0[0][nf]);
      acc0[1][nf] = MFMA16(ad[1], bk, acc0[1][nf]);
      acc1[0][nf] = MFMA16(cd[0], bq, acc1[0][nf]);
      acc1[1][nf] = MFMA16(cd[1], bq, acc1[1][nf]);
    }
  }
  float s0 = 0.f, s1 = 0.f;
#pragma unroll
  for (int i = 0; i < 2; ++i)
#pragma unroll
    for (int nf = 0; nf < 8; ++nf)
#pragma unroll
      for (int j = 0; j < 4; ++j) {
        s0 += fabsf(acc0[i][nf][j]);
        s1 += fabsf(acc1[i][nf][j]);
      }
#pragma unroll
  for (int off = 1; off < 64; off <<= 1) {
    s0 += __shfl_xor(s0, off, 64);
    s1 += __shfl_xor(s1, off, 64);
  }
  if (l == 0) { red[w] = s0; red[4 + w] = s1; }
  __syncthreads();
  if (t == 0) {
    partial[((size_t)0 * 16 + b) * 256 + ltm] = red[0] + red[1] + red[2] + red[3];
    partial[((size_t)1 * 16 + b) * 256 + ltm] = red[4] + red[5] + red[6] + red[7];
  }
}

__global__ void norm_reduce_kernel(const float* __restrict__ partial, float* __restrict__ outp)
{
  __shared__ float red[4];
  int t = threadIdx.x;
  float s = 0.f;
  for (int i = t; i < 8192; i += 256) s += partial[i];
#pragma unroll
  for (int off = 1; off < 64; off <<= 1) s += __shfl_xor(s, off, 64);
  if ((t & 63) == 0) red[t >> 6] = s;
  __syncthreads();
  if (t == 0) outp[0] = red[0] + red[1] + red[2] + red[3];
}

// ---------------------------------------------------------------- launch
extern "C" void kernel_launch(void* const* d_in, const int* in_sizes, int n_in,
                              void* d_out, int out_size, void* d_ws, size_t ws_size,
                              hipStream_t stream)
{
  const float* query = (const float*)d_in[0];
  const float* key_  = (const float*)d_in[1];
  const float* value = (const float*)d_in[2];
  const float* sf    = (const float*)d_in[3];
  const float* pos   = (const float*)d_in[4];
  const float* Wq  = (const float*)d_in[5];  const float* bq  = (const float*)d_in[6];
  const float* Wk  = (const float*)d_in[7];  const float* bk  = (const float*)d_in[8];
  const float* Wv  = (const float*)d_in[9];  const float* bv  = (const float*)d_in[10];
  const float* W1  = (const float*)d_in[11]; const float* b1  = (const float*)d_in[12];
  const float* W2  = (const float*)d_in[13]; const float* b2  = (const float*)d_in[14];
  const float* Wqc = (const float*)d_in[15]; const float* bqc = (const float*)d_in[16];
  const float* Wkc = (const float*)d_in[17]; const float* bkc = (const float*)d_in[18];
  float* out = (float*)d_out;

  char* ws = (char*)d_ws;
  size_t off = 0;
  auto alloc = [&](size_t bytes) {
    char* p = ws + off;
    off += (bytes + 255) & ~(size_t)255;
    return p;
  };
  unsigned short* Wf   = (unsigned short*)alloc((size_t)3 * 131072 * 2);
  unsigned short* Ut   = (unsigned short*)alloc((size_t)256 * 128 * 2);
  float* cqck          = (float*)alloc(256 * 4);
  float* Asf           = (float*)alloc(16 * 128 * 4);
  float* Ppos          = (float*)alloc((size_t)2048 * 128 * 4);
  unsigned short* qbf  = (unsigned short*)alloc((size_t)32768 * 128 * 2);
  unsigned short* kbf  = (unsigned short*)alloc((size_t)32768 * 128 * 2);
  unsigned short* vt   = (unsigned short*)alloc((size_t)32768 * 128 * 2);
  unsigned short* qc   = (unsigned short*)alloc((size_t)32768 * 128 * 2);
  unsigned short* kc   = (unsigned short*)alloc((size_t)32768 * 128 * 2);
  float* M2p           = (float*)alloc((size_t)8 * 262144 * 4);
  float* M2t           = (float*)alloc((size_t)262144 * 4);
  float* npartial      = (float*)alloc((size_t)8192 * 4);
  (void)ws_size; (void)in_sizes; (void)n_in; (void)out_size;

  prep_kernel<<<2577, 256, 0, stream>>>(Wq, Wk, Wv, W1, b1, W2, b2, Wqc, bqc, Wkc, bkc,
                                        sf, pos, Wf, Ut, cqck, Asf, Ppos);
  proj_kernel<<<dim3(2048, 3), 256, 0, stream>>>(query, key_, value, Wf, bq, bk, bv,
                                                 qbf, kbf, vt);
  qckc_kernel<<<512, 256, 0, stream>>>(Asf, Ppos, Ut, cqck, qc, kc);
  m2_partial_kernel<<<dim3(8, 16), 256, 0, stream>>>(vt, kc, M2p);
  m2_reduce_kernel<<<1024, 256, 0, stream>>>(M2p, M2t);
  attn_kernel<<<512, 256, 0, stream>>>(qbf, kbf, vt, qc, M2t, out);
  norm_kernel<<<4096, 256, 0, stream>>>(qc, kc, npartial);
  norm_reduce_kernel<<<1, 256, 0, stream>>>(npartial, out + (size_t)4194304);
}